// Round 1
// baseline (1198.027 us; speedup 1.0000x reference)
//
#include <hip/hip_runtime.h>

constexpr int N_NODES = 50000;
constexpr int N_EDGES = 800000;
constexpr int D_IN    = 96;
constexpr int D_HID   = 256;
constexpr int N_HID   = 512;
constexpr int N_OUT   = 768;

typedef __attribute__((ext_vector_type(8))) short short8;
typedef __attribute__((ext_vector_type(4))) float floatx4;

static __device__ __forceinline__ unsigned short f2bf(float f) {
    unsigned u = __float_as_uint(f);
    u += 0x7FFF + ((u >> 16) & 1);
    return (unsigned short)(u >> 16);
}

// ---------------- K_t: build Wt[n][k] = bf16(Wcat[k][n]), k<96 -> W_rel, else W_root
__global__ __launch_bounds__(256) void k_transpose_w(const float* __restrict__ Wrel,
                                                     const float* __restrict__ Wroot,
                                                     unsigned short* __restrict__ wt) {
    int idx = blockIdx.x * 256 + threadIdx.x;          // 256*192 = 49152
    int k = idx % 192;
    int n = idx / 192;
    float v = (k < 96) ? Wrel[k * 256 + n] : Wroot[(k - 96) * 256 + n];
    wt[idx] = f2bf(v);
}

// ---------------- K1: scatter-add  agg[dst] += x[src]
__global__ __launch_bounds__(256) void k_scatter(const int* __restrict__ ei,
                                                 const float* __restrict__ x,
                                                 float* __restrict__ agg) {
    int idx = blockIdx.x * 256 + threadIdx.x;          // 800000*24 = 19,200,000
    int e = idx / 24;
    int c = idx - e * 24;
    int s = ei[e];
    int d = ei[N_EDGES + e];
    float4 v = reinterpret_cast<const float4*>(x)[s * 24 + c];
    float* ap = agg + d * 96 + c * 4;
    atomicAdd(ap + 0, v.x);
    atomicAdd(ap + 1, v.y);
    atomicAdd(ap + 2, v.z);
    atomicAdd(ap + 3, v.w);
}

// ---------------- K3: h = relu([agg|x] @ Wcat + b_rel), fused segment-max into g
// grid (391, 4), block 256 = 4 waves. Block tile 128 rows x 64 cols, wave tile 32x64.
__global__ __launch_bounds__(256) void k_gnn(const float* __restrict__ agg,
                                             const float* __restrict__ x,
                                             const unsigned short* __restrict__ wt,
                                             const float* __restrict__ b_rel,
                                             const int* __restrict__ batch,
                                             int* __restrict__ g_i) {
    const int tid  = threadIdx.x;
    const int lane = tid & 63;
    const int wave = tid >> 6;
    const int quad = lane >> 4;
    const int l15  = lane & 15;
    const int row_base = blockIdx.x * 128 + wave * 32;
    const int n0 = blockIdx.y * 64;

    floatx4 acc[2][4];
#pragma unroll
    for (int i = 0; i < 2; i++)
#pragma unroll
        for (int j = 0; j < 4; j++) acc[i][j] = (floatx4)0.0f;

#pragma unroll
    for (int kc = 0; kc < 6; kc++) {
        const int k0 = kc * 32 + quad * 8;             // k within [0,192)
        short8 af[2];
#pragma unroll
        for (int mf = 0; mf < 2; mf++) {
            int r = row_base + mf * 16 + l15;
            short8 a;
            if (r < N_NODES) {
                const float* sp = (kc < 3) ? (agg + r * 96 + k0)
                                           : (x + r * 96 + (k0 - 96));
                float4 u = reinterpret_cast<const float4*>(sp)[0];
                float4 v = reinterpret_cast<const float4*>(sp)[1];
                a[0] = (short)f2bf(u.x); a[1] = (short)f2bf(u.y);
                a[2] = (short)f2bf(u.z); a[3] = (short)f2bf(u.w);
                a[4] = (short)f2bf(v.x); a[5] = (short)f2bf(v.y);
                a[6] = (short)f2bf(v.z); a[7] = (short)f2bf(v.w);
            } else {
                a = (short8)0;
            }
            af[mf] = a;
        }
        short8 bf[4];
#pragma unroll
        for (int nf = 0; nf < 4; nf++) {
            int n = n0 + nf * 16 + l15;
            bf[nf] = *reinterpret_cast<const short8*>(wt + n * 192 + k0);
        }
#pragma unroll
        for (int mf = 0; mf < 2; mf++)
#pragma unroll
            for (int nf = 0; nf < 4; nf++)
                acc[mf][nf] = __builtin_amdgcn_mfma_f32_16x16x32_bf16(
                    af[mf], bf[nf], acc[mf][nf], 0, 0, 0);
    }

    // Epilogue: bias + relu + segment-max pool (atomicMax on non-negative floats as int)
    bool fast = (row_base + 31 < N_NODES) && (batch[row_base] == batch[row_base + 31]);
    if (fast) {
        int gid = batch[row_base];
#pragma unroll
        for (int nf = 0; nf < 4; nf++) {
            float m = acc[0][nf][0];
#pragma unroll
            for (int mf = 0; mf < 2; mf++)
#pragma unroll
                for (int r = 0; r < 4; r++) m = fmaxf(m, acc[mf][nf][r]);
            m = fmaxf(m, __shfl_xor(m, 16));
            m = fmaxf(m, __shfl_xor(m, 32));
            if (quad == 0) {
                int n = n0 + nf * 16 + l15;
                float v = fmaxf(m + b_rel[n], 0.0f);
                atomicMax(&g_i[gid * 256 + n], __float_as_int(v));
            }
        }
    } else {
#pragma unroll
        for (int mf = 0; mf < 2; mf++) {
            int rb = row_base + mf * 16 + quad * 4;
            if (rb >= N_NODES) continue;
            bool merged = (rb + 3 < N_NODES) && (batch[rb] == batch[rb + 3]);
            if (merged) {
                int gid = batch[rb];
#pragma unroll
                for (int nf = 0; nf < 4; nf++) {
                    float m = fmaxf(fmaxf(acc[mf][nf][0], acc[mf][nf][1]),
                                    fmaxf(acc[mf][nf][2], acc[mf][nf][3]));
                    int n = n0 + nf * 16 + l15;
                    float v = fmaxf(m + b_rel[n], 0.0f);
                    atomicMax(&g_i[gid * 256 + n], __float_as_int(v));
                }
            } else {
                for (int r = 0; r < 4; r++) {
                    int rg = rb + r;
                    if (rg >= N_NODES) break;
                    int gid = batch[rg];
#pragma unroll
                    for (int nf = 0; nf < 4; nf++) {
                        int n = n0 + nf * 16 + l15;
                        float v = fmaxf(acc[mf][nf][r] + b_rel[n], 0.0f);
                        atomicMax(&g_i[gid * 256 + n], __float_as_int(v));
                    }
                }
            }
        }
    }
}

// ---------------- K4: g2 = relu(g @ W1 + b1), one graph per block
__global__ __launch_bounds__(256) void k_mlp1(const float* __restrict__ g,
                                              const float* __restrict__ W1,
                                              const float* __restrict__ b1,
                                              float* __restrict__ g2) {
    __shared__ float sg[256];
    int m = blockIdx.x, t = threadIdx.x;
    sg[t] = g[m * 256 + t];
    __syncthreads();
    float a0 = 0.f, a1 = 0.f;
    for (int k4 = 0; k4 < 64; k4++) {
        float4 a = reinterpret_cast<const float4*>(sg)[k4];
        int k = k4 * 4;
        a0 += a.x * W1[(k + 0) * 512 + t];
        a1 += a.x * W1[(k + 0) * 512 + 256 + t];
        a0 += a.y * W1[(k + 1) * 512 + t];
        a1 += a.y * W1[(k + 1) * 512 + 256 + t];
        a0 += a.z * W1[(k + 2) * 512 + t];
        a1 += a.z * W1[(k + 2) * 512 + 256 + t];
        a0 += a.w * W1[(k + 3) * 512 + t];
        a1 += a.w * W1[(k + 3) * 512 + 256 + t];
    }
    g2[m * 512 + t]       = fmaxf(a0 + b1[t], 0.f);
    g2[m * 512 + 256 + t] = fmaxf(a1 + b1[256 + t], 0.f);
}

// ---------------- K5: out = g2 @ W2 + b2, 4 graphs per block, 64 blocks
__global__ __launch_bounds__(256) void k_mlp2(const float* __restrict__ g2,
                                              const float* __restrict__ W2,
                                              const float* __restrict__ b2,
                                              float* __restrict__ out) {
    __shared__ float sg[4 * 512];
    int b = blockIdx.x, t = threadIdx.x;
#pragma unroll
    for (int i = 0; i < 8; i++) sg[t + i * 256] = g2[b * 2048 + t + i * 256];
    __syncthreads();
    float acc[4][3];
#pragma unroll
    for (int r = 0; r < 4; r++)
#pragma unroll
        for (int c = 0; c < 3; c++) acc[r][c] = 0.f;
    for (int k4 = 0; k4 < 128; k4++) {
        float4 ar[4];
#pragma unroll
        for (int r = 0; r < 4; r++)
            ar[r] = reinterpret_cast<const float4*>(sg + r * 512)[k4];
#pragma unroll
        for (int j = 0; j < 4; j++) {
            int k = k4 * 4 + j;
            float w0 = W2[k * 768 + t];
            float w1 = W2[k * 768 + 256 + t];
            float w2 = W2[k * 768 + 512 + t];
#pragma unroll
            for (int r = 0; r < 4; r++) {
                float a = (j == 0) ? ar[r].x : (j == 1) ? ar[r].y : (j == 2) ? ar[r].z : ar[r].w;
                acc[r][0] += a * w0;
                acc[r][1] += a * w1;
                acc[r][2] += a * w2;
            }
        }
    }
#pragma unroll
    for (int r = 0; r < 4; r++)
#pragma unroll
        for (int c = 0; c < 3; c++)
            out[(b * 4 + r) * 768 + c * 256 + t] = acc[r][c] + b2[c * 256 + t];
}

extern "C" void kernel_launch(void* const* d_in, const int* in_sizes, int n_in,
                              void* d_out, int out_size, void* d_ws, size_t ws_size,
                              hipStream_t stream) {
    const float* x      = (const float*)d_in[0];
    const int*   ei     = (const int*)d_in[1];
    const int*   batch  = (const int*)d_in[2];
    const float* W_rel  = (const float*)d_in[3];
    const float* b_rel  = (const float*)d_in[4];
    const float* W_root = (const float*)d_in[5];
    const float* W1     = (const float*)d_in[6];
    const float* b1     = (const float*)d_in[7];
    const float* W2     = (const float*)d_in[8];
    const float* b2     = (const float*)d_in[9];
    float* out = (float*)d_out;

    char* ws = (char*)d_ws;
    float* agg           = (float*)(ws);                 // 50000*96*4  = 19,200,000 B
    float* g             = (float*)(ws + 19200000);      // 256*256*4   =    262,144 B
    float* g2            = (float*)(ws + 19462144);      // 256*512*4   =    524,288 B
    unsigned short* wt   = (unsigned short*)(ws + 19986432); // 256*192*2 = 98,304 B

    // zero agg + g (single contiguous region)
    hipMemsetAsync(ws, 0, 19200000 + 262144, stream);

    k_transpose_w<<<192, 256, 0, stream>>>(W_rel, W_root, wt);
    k_scatter<<<(N_EDGES * 24) / 256, 256, 0, stream>>>(ei, x, agg);
    k_gnn<<<dim3(391, 4), 256, 0, stream>>>(agg, x, wt, b_rel, batch, (int*)g);
    k_mlp1<<<256, 256, 0, stream>>>(g, W1, b1, g2);
    k_mlp2<<<64, 256, 0, stream>>>(g2, W2, b2, out);
}

// Round 2
// 378.078 us; speedup vs baseline: 3.1687x; 3.1687x over previous
//
#include <hip/hip_runtime.h>

constexpr int N_NODES = 50000;
constexpr int N_EDGES = 800000;
constexpr int D_IN    = 96;
constexpr int D_HID   = 256;
constexpr int N_HID   = 512;
constexpr int N_OUT   = 768;

typedef __attribute__((ext_vector_type(8))) short short8;
typedef __attribute__((ext_vector_type(4))) float floatx4;

static __device__ __forceinline__ unsigned short f2bf(float f) {
    unsigned u = __float_as_uint(f);
    u += 0x7FFF + ((u >> 16) & 1);
    return (unsigned short)(u >> 16);
}

// ---------------- K_t: build Wt[n][k] = bf16(Wcat[k][n])
__global__ __launch_bounds__(256) void k_transpose_w(const float* __restrict__ Wrel,
                                                     const float* __restrict__ Wroot,
                                                     unsigned short* __restrict__ wt) {
    int idx = blockIdx.x * 256 + threadIdx.x;          // 256*192 = 49152
    int k = idx % 192;
    int n = idx / 192;
    float v = (k < 96) ? Wrel[k * 256 + n] : Wroot[(k - 96) * 256 + n];
    wt[idx] = f2bf(v);
}

// ---------------- CSR build: histogram of dst
__global__ __launch_bounds__(256) void k_hist(const int* __restrict__ ei,
                                              int* __restrict__ deg) {
    int e = blockIdx.x * 256 + threadIdx.x;
    if (e < N_EDGES) atomicAdd(&deg[ei[N_EDGES + e]], 1);
}

// ---------------- CSR build: exclusive scan (single block, wave-shuffle hierarchical)
__global__ __launch_bounds__(1024) void k_scan(const int* __restrict__ deg,
                                               int* __restrict__ off,
                                               int* __restrict__ cur) {
    __shared__ int wsum[16];
    int t = threadIdx.x, lane = t & 63, w = t >> 6;
    int run = 0;
    for (int base = 0; base < N_NODES; base += 1024) {
        int i = base + t;
        int v = (i < N_NODES) ? deg[i] : 0;
        int s = v;
#pragma unroll
        for (int d = 1; d < 64; d <<= 1) {
            int o = __shfl_up(s, d);
            if (lane >= d) s += o;
        }
        if (lane == 63) wsum[w] = s;
        __syncthreads();
        if (t < 16) {
            int ws = wsum[t];
#pragma unroll
            for (int d = 1; d < 16; d <<= 1) {
                int o = __shfl_up(ws, d);
                if (t >= d) ws += o;
            }
            wsum[t] = ws;
        }
        __syncthreads();
        int wexc = (w == 0) ? 0 : wsum[w - 1];
        int excl = run + wexc + (s - v);
        if (i < N_NODES) { off[i] = excl; cur[i] = excl; }
        run += wsum[15];
        __syncthreads();
    }
    if (t == 0) off[N_NODES] = run;
}

// ---------------- CSR build: fill dst-sorted src list
__global__ __launch_bounds__(256) void k_fill(const int* __restrict__ ei,
                                              int* __restrict__ cur,
                                              int* __restrict__ es) {
    int e = blockIdx.x * 256 + threadIdx.x;
    if (e >= N_EDGES) return;
    int s = ei[e];
    int d = ei[N_EDGES + e];
    int p = atomicAdd(&cur[d], 1);
    es[p] = s;
}

// ---------------- gather-sum: agg[n] = sum over incoming edges of x[src]
// 24 threads per node, one float4 column chunk each.
__global__ __launch_bounds__(256) void k_gather(const int* __restrict__ off,
                                                const int* __restrict__ es,
                                                const float* __restrict__ x,
                                                float* __restrict__ agg) {
    int idx = blockIdx.x * 256 + threadIdx.x;
    if (idx >= N_NODES * 24) return;
    int n = idx / 24;
    int c = idx - n * 24;
    int o0 = off[n], o1 = off[n + 1];
    float4 acc = make_float4(0.f, 0.f, 0.f, 0.f);
    for (int e = o0; e < o1; e++) {
        int s = es[e];
        float4 v = reinterpret_cast<const float4*>(x)[s * 24 + c];
        acc.x += v.x; acc.y += v.y; acc.z += v.z; acc.w += v.w;
    }
    reinterpret_cast<float4*>(agg)[idx] = acc;
}

// ---------------- K3: h = relu([agg|x] @ Wcat + b_rel), fused segment-max into g
__global__ __launch_bounds__(256) void k_gnn(const float* __restrict__ agg,
                                             const float* __restrict__ x,
                                             const unsigned short* __restrict__ wt,
                                             const float* __restrict__ b_rel,
                                             const int* __restrict__ batch,
                                             int* __restrict__ g_i) {
    const int tid  = threadIdx.x;
    const int lane = tid & 63;
    const int wave = tid >> 6;
    const int quad = lane >> 4;
    const int l15  = lane & 15;
    const int row_base = blockIdx.x * 128 + wave * 32;
    const int n0 = blockIdx.y * 64;

    floatx4 acc[2][4];
#pragma unroll
    for (int i = 0; i < 2; i++)
#pragma unroll
        for (int j = 0; j < 4; j++) acc[i][j] = (floatx4)0.0f;

#pragma unroll
    for (int kc = 0; kc < 6; kc++) {
        const int k0 = kc * 32 + quad * 8;
        short8 af[2];
#pragma unroll
        for (int mf = 0; mf < 2; mf++) {
            int r = row_base + mf * 16 + l15;
            short8 a;
            if (r < N_NODES) {
                const float* sp = (kc < 3) ? (agg + r * 96 + k0)
                                           : (x + r * 96 + (k0 - 96));
                float4 u = reinterpret_cast<const float4*>(sp)[0];
                float4 v = reinterpret_cast<const float4*>(sp)[1];
                a[0] = (short)f2bf(u.x); a[1] = (short)f2bf(u.y);
                a[2] = (short)f2bf(u.z); a[3] = (short)f2bf(u.w);
                a[4] = (short)f2bf(v.x); a[5] = (short)f2bf(v.y);
                a[6] = (short)f2bf(v.z); a[7] = (short)f2bf(v.w);
            } else {
                a = (short8)0;
            }
            af[mf] = a;
        }
        short8 bf[4];
#pragma unroll
        for (int nf = 0; nf < 4; nf++) {
            int n = n0 + nf * 16 + l15;
            bf[nf] = *reinterpret_cast<const short8*>(wt + n * 192 + k0);
        }
#pragma unroll
        for (int mf = 0; mf < 2; mf++)
#pragma unroll
            for (int nf = 0; nf < 4; nf++)
                acc[mf][nf] = __builtin_amdgcn_mfma_f32_16x16x32_bf16(
                    af[mf], bf[nf], acc[mf][nf], 0, 0, 0);
    }

    bool fast = (row_base + 31 < N_NODES) && (batch[row_base] == batch[row_base + 31]);
    if (fast) {
        int gid = batch[row_base];
#pragma unroll
        for (int nf = 0; nf < 4; nf++) {
            float m = acc[0][nf][0];
#pragma unroll
            for (int mf = 0; mf < 2; mf++)
#pragma unroll
                for (int r = 0; r < 4; r++) m = fmaxf(m, acc[mf][nf][r]);
            m = fmaxf(m, __shfl_xor(m, 16));
            m = fmaxf(m, __shfl_xor(m, 32));
            if (quad == 0) {
                int n = n0 + nf * 16 + l15;
                float v = fmaxf(m + b_rel[n], 0.0f);
                atomicMax(&g_i[gid * 256 + n], __float_as_int(v));
            }
        }
    } else {
#pragma unroll
        for (int mf = 0; mf < 2; mf++) {
            int rb = row_base + mf * 16 + quad * 4;
            if (rb >= N_NODES) continue;
            bool merged = (rb + 3 < N_NODES) && (batch[rb] == batch[rb + 3]);
            if (merged) {
                int gid = batch[rb];
#pragma unroll
                for (int nf = 0; nf < 4; nf++) {
                    float m = fmaxf(fmaxf(acc[mf][nf][0], acc[mf][nf][1]),
                                    fmaxf(acc[mf][nf][2], acc[mf][nf][3]));
                    int n = n0 + nf * 16 + l15;
                    float v = fmaxf(m + b_rel[n], 0.0f);
                    atomicMax(&g_i[gid * 256 + n], __float_as_int(v));
                }
            } else {
                for (int r = 0; r < 4; r++) {
                    int rg = rb + r;
                    if (rg >= N_NODES) break;
                    int gid = batch[rg];
#pragma unroll
                    for (int nf = 0; nf < 4; nf++) {
                        int n = n0 + nf * 16 + l15;
                        float v = fmaxf(acc[mf][nf][r] + b_rel[n], 0.0f);
                        atomicMax(&g_i[gid * 256 + n], __float_as_int(v));
                    }
                }
            }
        }
    }
}

// ---------------- K4: g2 = relu(g @ W1 + b1)
__global__ __launch_bounds__(256) void k_mlp1(const float* __restrict__ g,
                                              const float* __restrict__ W1,
                                              const float* __restrict__ b1,
                                              float* __restrict__ g2) {
    __shared__ float sg[256];
    int m = blockIdx.x, t = threadIdx.x;
    sg[t] = g[m * 256 + t];
    __syncthreads();
    float a0 = 0.f, a1 = 0.f;
    for (int k4 = 0; k4 < 64; k4++) {
        float4 a = reinterpret_cast<const float4*>(sg)[k4];
        int k = k4 * 4;
        a0 += a.x * W1[(k + 0) * 512 + t];
        a1 += a.x * W1[(k + 0) * 512 + 256 + t];
        a0 += a.y * W1[(k + 1) * 512 + t];
        a1 += a.y * W1[(k + 1) * 512 + 256 + t];
        a0 += a.z * W1[(k + 2) * 512 + t];
        a1 += a.z * W1[(k + 2) * 512 + 256 + t];
        a0 += a.w * W1[(k + 3) * 512 + t];
        a1 += a.w * W1[(k + 3) * 512 + 256 + t];
    }
    g2[m * 512 + t]       = fmaxf(a0 + b1[t], 0.f);
    g2[m * 512 + 256 + t] = fmaxf(a1 + b1[256 + t], 0.f);
}

// ---------------- K5: out = g2 @ W2 + b2
__global__ __launch_bounds__(256) void k_mlp2(const float* __restrict__ g2,
                                              const float* __restrict__ W2,
                                              const float* __restrict__ b2,
                                              float* __restrict__ out) {
    __shared__ float sg[4 * 512];
    int b = blockIdx.x, t = threadIdx.x;
#pragma unroll
    for (int i = 0; i < 8; i++) sg[t + i * 256] = g2[b * 2048 + t + i * 256];
    __syncthreads();
    float acc[4][3];
#pragma unroll
    for (int r = 0; r < 4; r++)
#pragma unroll
        for (int c = 0; c < 3; c++) acc[r][c] = 0.f;
    for (int k4 = 0; k4 < 128; k4++) {
        float4 ar[4];
#pragma unroll
        for (int r = 0; r < 4; r++)
            ar[r] = reinterpret_cast<const float4*>(sg + r * 512)[k4];
#pragma unroll
        for (int j = 0; j < 4; j++) {
            int k = k4 * 4 + j;
            float w0 = W2[k * 768 + t];
            float w1 = W2[k * 768 + 256 + t];
            float w2 = W2[k * 768 + 512 + t];
#pragma unroll
            for (int r = 0; r < 4; r++) {
                float a = (j == 0) ? ar[r].x : (j == 1) ? ar[r].y : (j == 2) ? ar[r].z : ar[r].w;
                acc[r][0] += a * w0;
                acc[r][1] += a * w1;
                acc[r][2] += a * w2;
            }
        }
    }
#pragma unroll
    for (int r = 0; r < 4; r++)
#pragma unroll
        for (int c = 0; c < 3; c++)
            out[(b * 4 + r) * 768 + c * 256 + t] = acc[r][c] + b2[c * 256 + t];
}

extern "C" void kernel_launch(void* const* d_in, const int* in_sizes, int n_in,
                              void* d_out, int out_size, void* d_ws, size_t ws_size,
                              hipStream_t stream) {
    const float* x      = (const float*)d_in[0];
    const int*   ei     = (const int*)d_in[1];
    const int*   batch  = (const int*)d_in[2];
    const float* W_rel  = (const float*)d_in[3];
    const float* b_rel  = (const float*)d_in[4];
    const float* W_root = (const float*)d_in[5];
    const float* W1     = (const float*)d_in[6];
    const float* b1     = (const float*)d_in[7];
    const float* W2     = (const float*)d_in[8];
    const float* b2     = (const float*)d_in[9];
    float* out = (float*)d_out;

    char* ws = (char*)d_ws;
    float* agg = (float*)(ws);                       // 19,200,000 B
    float* g   = (float*)(ws + 19200000);            //    262,144 B
    int*   deg = (int*)  (ws + 19462144);            //    200,000 B
    int*   off = (int*)  (ws + 19662144);            //    200,016 B (50001 ints)
    int*   cur = (int*)  (ws + 19862160);            //    200,000 B
    int*   es  = (int*)  (ws + 20062160);            //  3,200,000 B
    float* g2  = (float*)(ws + 23262160);            //    524,288 B
    unsigned short* wt = (unsigned short*)(ws + 23786448); // 98,304 B

    // zero g (for atomicMax) and deg (for histogram) — contiguous
    hipMemsetAsync(ws + 19200000, 0, 262144 + 200000, stream);

    k_transpose_w<<<192, 256, 0, stream>>>(W_rel, W_root, wt);
    k_hist<<<(N_EDGES + 255) / 256, 256, 0, stream>>>(ei, deg);
    k_scan<<<1, 1024, 0, stream>>>(deg, off, cur);
    k_fill<<<(N_EDGES + 255) / 256, 256, 0, stream>>>(ei, cur, es);
    k_gather<<<(N_NODES * 24 + 255) / 256, 256, 0, stream>>>(off, es, x, agg);
    k_gnn<<<dim3(391, 4), 256, 0, stream>>>(agg, x, wt, b_rel, batch, (int*)g);
    k_mlp1<<<256, 256, 0, stream>>>(g, W1, b1, g2);
    k_mlp2<<<64, 256, 0, stream>>>(g2, W2, b2, out);
}

// Round 3
// 331.366 us; speedup vs baseline: 3.6154x; 1.1410x over previous
//
#include <hip/hip_runtime.h>

constexpr int N_NODES = 50000;
constexpr int N_EDGES = 800000;
constexpr int D_IN    = 96;
constexpr int D_HID   = 256;
constexpr int N_HID   = 512;
constexpr int N_OUT   = 768;

typedef __attribute__((ext_vector_type(8))) short short8;
typedef __attribute__((ext_vector_type(4))) float floatx4;

static __device__ __forceinline__ unsigned short f2bf(float f) {
    unsigned u = __float_as_uint(f);
    u += 0x7FFF + ((u >> 16) & 1);
    return (unsigned short)(u >> 16);
}

// ---------------- K_t: build Wt[n][k] = bf16(Wcat[k][n])
__global__ __launch_bounds__(256) void k_transpose_w(const float* __restrict__ Wrel,
                                                     const float* __restrict__ Wroot,
                                                     unsigned short* __restrict__ wt) {
    int idx = blockIdx.x * 256 + threadIdx.x;          // 256*192 = 49152
    int k = idx % 192;
    int n = idx / 192;
    float v = (k < 96) ? Wrel[k * 256 + n] : Wroot[(k - 96) * 256 + n];
    wt[idx] = f2bf(v);
}

// ---------------- CSR build: histogram of dst
__global__ __launch_bounds__(256) void k_hist(const int* __restrict__ ei,
                                              int* __restrict__ deg) {
    int e = blockIdx.x * 256 + threadIdx.x;
    if (e < N_EDGES) atomicAdd(&deg[ei[N_EDGES + e]], 1);
}

// ---------------- CSR build: exclusive scan (single block, wave-shuffle hierarchical)
__global__ __launch_bounds__(1024) void k_scan(const int* __restrict__ deg,
                                               int* __restrict__ off,
                                               int* __restrict__ cur) {
    __shared__ int wsum[16];
    int t = threadIdx.x, lane = t & 63, w = t >> 6;
    int run = 0;
    for (int base = 0; base < N_NODES; base += 1024) {
        int i = base + t;
        int v = (i < N_NODES) ? deg[i] : 0;
        int s = v;
#pragma unroll
        for (int d = 1; d < 64; d <<= 1) {
            int o = __shfl_up(s, d);
            if (lane >= d) s += o;
        }
        if (lane == 63) wsum[w] = s;
        __syncthreads();
        if (t < 16) {
            int ws = wsum[t];
#pragma unroll
            for (int d = 1; d < 16; d <<= 1) {
                int o = __shfl_up(ws, d);
                if (t >= d) ws += o;
            }
            wsum[t] = ws;
        }
        __syncthreads();
        int wexc = (w == 0) ? 0 : wsum[w - 1];
        int excl = run + wexc + (s - v);
        if (i < N_NODES) { off[i] = excl; cur[i] = excl; }
        run += wsum[15];
        __syncthreads();
    }
    if (t == 0) off[N_NODES] = run;
}

// ---------------- CSR build: fill dst-sorted src list
__global__ __launch_bounds__(256) void k_fill(const int* __restrict__ ei,
                                              int* __restrict__ cur,
                                              int* __restrict__ es) {
    int e = blockIdx.x * 256 + threadIdx.x;
    if (e >= N_EDGES) return;
    int s = ei[e];
    int d = ei[N_EDGES + e];
    int p = atomicAdd(&cur[d], 1);
    es[p] = s;
}

// ---------------- gather-sum: agg[n] = sum over incoming edges of x[src]
// 24 threads per node, one float4 column chunk each; edge loop unrolled x2.
__global__ __launch_bounds__(256) void k_gather(const int* __restrict__ off,
                                                const int* __restrict__ es,
                                                const float* __restrict__ x,
                                                float* __restrict__ agg) {
    int idx = blockIdx.x * 256 + threadIdx.x;
    if (idx >= N_NODES * 24) return;
    int n = idx / 24;
    int c = idx - n * 24;
    int o0 = off[n], o1 = off[n + 1];
    float4 acc = make_float4(0.f, 0.f, 0.f, 0.f);
    int e = o0;
    for (; e + 2 <= o1; e += 2) {
        int s0 = es[e], s1 = es[e + 1];
        float4 v0 = reinterpret_cast<const float4*>(x)[s0 * 24 + c];
        float4 v1 = reinterpret_cast<const float4*>(x)[s1 * 24 + c];
        acc.x += v0.x; acc.y += v0.y; acc.z += v0.z; acc.w += v0.w;
        acc.x += v1.x; acc.y += v1.y; acc.z += v1.z; acc.w += v1.w;
    }
    if (e < o1) {
        int s0 = es[e];
        float4 v0 = reinterpret_cast<const float4*>(x)[s0 * 24 + c];
        acc.x += v0.x; acc.y += v0.y; acc.z += v0.z; acc.w += v0.w;
    }
    reinterpret_cast<float4*>(agg)[idx] = acc;
}

// ---------------- K3: h = relu([agg|x] @ Wcat + b_rel), fused segment-max into g
__global__ __launch_bounds__(256) void k_gnn(const float* __restrict__ agg,
                                             const float* __restrict__ x,
                                             const unsigned short* __restrict__ wt,
                                             const float* __restrict__ b_rel,
                                             const int* __restrict__ batch,
                                             int* __restrict__ g_i) {
    const int tid  = threadIdx.x;
    const int lane = tid & 63;
    const int wave = tid >> 6;
    const int quad = lane >> 4;
    const int l15  = lane & 15;
    const int row_base = blockIdx.x * 128 + wave * 32;
    const int n0 = blockIdx.y * 64;

    floatx4 acc[2][4];
#pragma unroll
    for (int i = 0; i < 2; i++)
#pragma unroll
        for (int j = 0; j < 4; j++) acc[i][j] = (floatx4)0.0f;

#pragma unroll
    for (int kc = 0; kc < 6; kc++) {
        const int k0 = kc * 32 + quad * 8;
        short8 af[2];
#pragma unroll
        for (int mf = 0; mf < 2; mf++) {
            int r = row_base + mf * 16 + l15;
            short8 a;
            if (r < N_NODES) {
                const float* sp = (kc < 3) ? (agg + r * 96 + k0)
                                           : (x + r * 96 + (k0 - 96));
                float4 u = reinterpret_cast<const float4*>(sp)[0];
                float4 v = reinterpret_cast<const float4*>(sp)[1];
                a[0] = (short)f2bf(u.x); a[1] = (short)f2bf(u.y);
                a[2] = (short)f2bf(u.z); a[3] = (short)f2bf(u.w);
                a[4] = (short)f2bf(v.x); a[5] = (short)f2bf(v.y);
                a[6] = (short)f2bf(v.z); a[7] = (short)f2bf(v.w);
            } else {
                a = (short8)0;
            }
            af[mf] = a;
        }
        short8 bf[4];
#pragma unroll
        for (int nf = 0; nf < 4; nf++) {
            int n = n0 + nf * 16 + l15;
            bf[nf] = *reinterpret_cast<const short8*>(wt + n * 192 + k0);
        }
#pragma unroll
        for (int mf = 0; mf < 2; mf++)
#pragma unroll
            for (int nf = 0; nf < 4; nf++)
                acc[mf][nf] = __builtin_amdgcn_mfma_f32_16x16x32_bf16(
                    af[mf], bf[nf], acc[mf][nf], 0, 0, 0);
    }

    bool fast = (row_base + 31 < N_NODES) && (batch[row_base] == batch[row_base + 31]);
    if (fast) {
        int gid = batch[row_base];
#pragma unroll
        for (int nf = 0; nf < 4; nf++) {
            float m = acc[0][nf][0];
#pragma unroll
            for (int mf = 0; mf < 2; mf++)
#pragma unroll
                for (int r = 0; r < 4; r++) m = fmaxf(m, acc[mf][nf][r]);
            m = fmaxf(m, __shfl_xor(m, 16));
            m = fmaxf(m, __shfl_xor(m, 32));
            if (quad == 0) {
                int n = n0 + nf * 16 + l15;
                float v = fmaxf(m + b_rel[n], 0.0f);
                atomicMax(&g_i[gid * 256 + n], __float_as_int(v));
            }
        }
    } else {
#pragma unroll
        for (int mf = 0; mf < 2; mf++) {
            int rb = row_base + mf * 16 + quad * 4;
            if (rb >= N_NODES) continue;
            bool merged = (rb + 3 < N_NODES) && (batch[rb] == batch[rb + 3]);
            if (merged) {
                int gid = batch[rb];
#pragma unroll
                for (int nf = 0; nf < 4; nf++) {
                    float m = fmaxf(fmaxf(acc[mf][nf][0], acc[mf][nf][1]),
                                    fmaxf(acc[mf][nf][2], acc[mf][nf][3]));
                    int n = n0 + nf * 16 + l15;
                    float v = fmaxf(m + b_rel[n], 0.0f);
                    atomicMax(&g_i[gid * 256 + n], __float_as_int(v));
                }
            } else {
                for (int r = 0; r < 4; r++) {
                    int rg = rb + r;
                    if (rg >= N_NODES) break;
                    int gid = batch[rg];
#pragma unroll
                    for (int nf = 0; nf < 4; nf++) {
                        int n = n0 + nf * 16 + l15;
                        float v = fmaxf(acc[mf][nf][r] + b_rel[n], 0.0f);
                        atomicMax(&g_i[gid * 256 + n], __float_as_int(v));
                    }
                }
            }
        }
    }
}

// ---------------- K4: g2 = relu(g @ W1 + b1). grid 512: (graph, n-half). 1 out/thread.
__global__ __launch_bounds__(256) void k_mlp1(const float* __restrict__ g,
                                              const float* __restrict__ W1,
                                              const float* __restrict__ b1,
                                              float* __restrict__ g2) {
    __shared__ float sg[256];
    int m  = blockIdx.x >> 1;
    int nh = (blockIdx.x & 1) * 256;
    int t  = threadIdx.x;
    sg[t] = g[m * 256 + t];
    __syncthreads();
    int n = nh + t;
    float acc = 0.f;
#pragma unroll 4
    for (int k4 = 0; k4 < 64; k4++) {
        float4 a = reinterpret_cast<const float4*>(sg)[k4];
        int k = k4 * 4;
        float w0 = W1[(k + 0) * 512 + n];
        float w1 = W1[(k + 1) * 512 + n];
        float w2 = W1[(k + 2) * 512 + n];
        float w3 = W1[(k + 3) * 512 + n];
        acc += a.x * w0 + a.y * w1 + a.z * w2 + a.w * w3;
    }
    g2[m * 512 + n] = fmaxf(acc + b1[n], 0.f);
}

// ---------------- K5: out = g2 @ W2 + b2. grid (128,3): 2 graphs x 256 outs/block.
__global__ __launch_bounds__(256) void k_mlp2(const float* __restrict__ g2,
                                              const float* __restrict__ W2,
                                              const float* __restrict__ b2,
                                              float* __restrict__ out) {
    __shared__ float sg[2 * 512];
    int m0 = blockIdx.x * 2;
    int n  = blockIdx.y * 256 + threadIdx.x;
    int t  = threadIdx.x;
#pragma unroll
    for (int i = 0; i < 4; i++) sg[t + i * 256] = g2[m0 * 512 + t + i * 256];
    __syncthreads();
    float a0 = 0.f, a1 = 0.f;
#pragma unroll 4
    for (int k4 = 0; k4 < 128; k4++) {
        float4 u = reinterpret_cast<const float4*>(sg)[k4];
        float4 v = reinterpret_cast<const float4*>(sg + 512)[k4];
        int k = k4 * 4;
        float w0 = W2[(k + 0) * 768 + n];
        float w1 = W2[(k + 1) * 768 + n];
        float w2 = W2[(k + 2) * 768 + n];
        float w3 = W2[(k + 3) * 768 + n];
        a0 += u.x * w0 + u.y * w1 + u.z * w2 + u.w * w3;
        a1 += v.x * w0 + v.y * w1 + v.z * w2 + v.w * w3;
    }
    float b = b2[n];
    out[(m0 + 0) * 768 + n] = a0 + b;
    out[(m0 + 1) * 768 + n] = a1 + b;
}

extern "C" void kernel_launch(void* const* d_in, const int* in_sizes, int n_in,
                              void* d_out, int out_size, void* d_ws, size_t ws_size,
                              hipStream_t stream) {
    const float* x      = (const float*)d_in[0];
    const int*   ei     = (const int*)d_in[1];
    const int*   batch  = (const int*)d_in[2];
    const float* W_rel  = (const float*)d_in[3];
    const float* b_rel  = (const float*)d_in[4];
    const float* W_root = (const float*)d_in[5];
    const float* W1     = (const float*)d_in[6];
    const float* b1     = (const float*)d_in[7];
    const float* W2     = (const float*)d_in[8];
    const float* b2     = (const float*)d_in[9];
    float* out = (float*)d_out;

    char* ws = (char*)d_ws;
    float* agg = (float*)(ws);                       // 19,200,000 B
    float* g   = (float*)(ws + 19200000);            //    262,144 B
    int*   deg = (int*)  (ws + 19462144);            //    200,000 B
    int*   off = (int*)  (ws + 19662144);            //    200,016 B (50001 ints)
    int*   cur = (int*)  (ws + 19862160);            //    200,000 B
    int*   es  = (int*)  (ws + 20062160);            //  3,200,000 B
    float* g2  = (float*)(ws + 23262160);            //    524,288 B
    unsigned short* wt = (unsigned short*)(ws + 23786448); // 98,304 B

    // zero g (for atomicMax) and deg (for histogram) — contiguous
    hipMemsetAsync(ws + 19200000, 0, 262144 + 200000, stream);

    k_transpose_w<<<192, 256, 0, stream>>>(W_rel, W_root, wt);
    k_hist<<<(N_EDGES + 255) / 256, 256, 0, stream>>>(ei, deg);
    k_scan<<<1, 1024, 0, stream>>>(deg, off, cur);
    k_fill<<<(N_EDGES + 255) / 256, 256, 0, stream>>>(ei, cur, es);
    k_gather<<<(N_NODES * 24 + 255) / 256, 256, 0, stream>>>(off, es, x, agg);
    k_gnn<<<dim3(391, 4), 256, 0, stream>>>(agg, x, wt, b_rel, batch, (int*)g);
    k_mlp1<<<512, 256, 0, stream>>>(g, W1, b1, g2);
    k_mlp2<<<dim3(128, 3), 256, 0, stream>>>(g2, W2, b2, out);
}

// Round 4
// 310.350 us; speedup vs baseline: 3.8602x; 1.0677x over previous
//
#include <hip/hip_runtime.h>

constexpr int N_NODES = 50000;
constexpr int N_EDGES = 800000;

typedef __attribute__((ext_vector_type(8))) short short8;
typedef __attribute__((ext_vector_type(8))) unsigned short ushort8;
typedef __attribute__((ext_vector_type(4))) float floatx4;

static __device__ __forceinline__ unsigned short f2bf(float f) {
    unsigned u = __float_as_uint(f);
    u += 0x7FFF + ((u >> 16) & 1);
    return (unsigned short)(u >> 16);
}
static __device__ __forceinline__ float bf2f(unsigned short s) {
    return __uint_as_float(((unsigned)s) << 16);
}

// ---------------- K_p: x fp32 -> x_bf bf16 (8 elems/thread)
__global__ __launch_bounds__(256) void k_prep(const float* __restrict__ x,
                                              unsigned short* __restrict__ xb) {
    int idx = blockIdx.x * 256 + threadIdx.x;          // 600000 chunks of 8
    if (idx >= N_NODES * 96 / 8) return;
    const float4* p = reinterpret_cast<const float4*>(x) + idx * 2;
    float4 u = p[0], v = p[1];
    short8 a;
    a[0] = (short)f2bf(u.x); a[1] = (short)f2bf(u.y);
    a[2] = (short)f2bf(u.z); a[3] = (short)f2bf(u.w);
    a[4] = (short)f2bf(v.x); a[5] = (short)f2bf(v.y);
    a[6] = (short)f2bf(v.z); a[7] = (short)f2bf(v.w);
    reinterpret_cast<short8*>(xb)[idx] = a;
}

// ---------------- K_t: build Wt[n][k] = bf16(Wcat[k][n])
__global__ __launch_bounds__(256) void k_transpose_w(const float* __restrict__ Wrel,
                                                     const float* __restrict__ Wroot,
                                                     unsigned short* __restrict__ wt) {
    int idx = blockIdx.x * 256 + threadIdx.x;          // 256*192 = 49152
    int k = idx % 192;
    int n = idx / 192;
    float v = (k < 96) ? Wrel[k * 256 + n] : Wroot[(k - 96) * 256 + n];
    wt[idx] = f2bf(v);
}

// ---------------- CSR build: histogram of dst
__global__ __launch_bounds__(256) void k_hist(const int* __restrict__ ei,
                                              int* __restrict__ deg) {
    int e = blockIdx.x * 256 + threadIdx.x;
    if (e < N_EDGES) atomicAdd(&deg[ei[N_EDGES + e]], 1);
}

// ---------------- CSR build: exclusive scan, 4 elems/thread (13 iters)
__global__ __launch_bounds__(1024) void k_scan(const int* __restrict__ deg,
                                               int* __restrict__ off,
                                               int* __restrict__ cur) {
    __shared__ int wsum[16];
    int t = threadIdx.x, lane = t & 63, w = t >> 6;
    int run = 0;
    for (int base = 0; base < N_NODES; base += 4096) {
        int i = base + t * 4;
        int4 d = make_int4(0, 0, 0, 0);
        if (i < N_NODES) d = reinterpret_cast<const int4*>(deg + i)[0];
        int v = d.x + d.y + d.z + d.w;
        int s = v;
#pragma unroll
        for (int dd = 1; dd < 64; dd <<= 1) {
            int o = __shfl_up(s, dd);
            if (lane >= dd) s += o;
        }
        if (lane == 63) wsum[w] = s;
        __syncthreads();
        if (t < 16) {
            int ws = wsum[t];
#pragma unroll
            for (int dd = 1; dd < 16; dd <<= 1) {
                int o = __shfl_up(ws, dd);
                if (t >= dd) ws += o;
            }
            wsum[t] = ws;
        }
        __syncthreads();
        int wexc = (w == 0) ? 0 : wsum[w - 1];
        int e0 = run + wexc + (s - v);
        if (i < N_NODES) {
            int4 o;
            o.x = e0; o.y = o.x + d.x; o.z = o.y + d.y; o.w = o.z + d.z;
            reinterpret_cast<int4*>(off + i)[0] = o;
            reinterpret_cast<int4*>(cur + i)[0] = o;
        }
        run += wsum[15];
        __syncthreads();
    }
    if (t == 0) off[N_NODES] = run;
}

// ---------------- CSR build: fill dst-sorted src list (atomicExch store: memory-side,
// avoids partial-line writeback cost of scattered plain stores)
__global__ __launch_bounds__(256) void k_fill(const int* __restrict__ ei,
                                              int* __restrict__ cur,
                                              int* __restrict__ es) {
    int e = blockIdx.x * 256 + threadIdx.x;
    if (e >= N_EDGES) return;
    int s = ei[e];
    int d = ei[N_EDGES + e];
    int p = atomicAdd(&cur[d], 1);
    atomicExch(&es[p], s);
}

// ---------------- gather-sum (bf16 in / bf16 out, fp32 accum)
// 12 threads per node, one 16B chunk each; edge loop unrolled x2.
__global__ __launch_bounds__(256) void k_gather(const int* __restrict__ off,
                                                const int* __restrict__ es,
                                                const unsigned short* __restrict__ xb,
                                                unsigned short* __restrict__ aggb) {
    int idx = blockIdx.x * 256 + threadIdx.x;
    if (idx >= N_NODES * 12) return;
    int n = idx / 12;
    int c = idx - n * 12;
    int o0 = off[n], o1 = off[n + 1];
    const ushort8* xv = reinterpret_cast<const ushort8*>(xb);
    float acc[8];
#pragma unroll
    for (int j = 0; j < 8; j++) acc[j] = 0.f;
    int e = o0;
    for (; e + 2 <= o1; e += 2) {
        int s0 = es[e], s1 = es[e + 1];
        ushort8 a = xv[s0 * 12 + c];
        ushort8 b = xv[s1 * 12 + c];
#pragma unroll
        for (int j = 0; j < 8; j++) acc[j] += bf2f(a[j]);
#pragma unroll
        for (int j = 0; j < 8; j++) acc[j] += bf2f(b[j]);
    }
    if (e < o1) {
        ushort8 a = xv[es[e] * 12 + c];
#pragma unroll
        for (int j = 0; j < 8; j++) acc[j] += bf2f(a[j]);
    }
    short8 r;
#pragma unroll
    for (int j = 0; j < 8; j++) r[j] = (short)f2bf(acc[j]);
    reinterpret_cast<short8*>(aggb)[idx] = r;
}

// ---------------- K3: h = relu([agg|x] @ Wcat + b_rel), fused segment-max into g
// grid 391 blocks, 4 waves x 32 rows. A-frags loaded ONCE into regs; loop 4 n-slices.
__global__ __launch_bounds__(256, 3) void k_gnn(const unsigned short* __restrict__ aggb,
                                                const unsigned short* __restrict__ xb,
                                                const unsigned short* __restrict__ wt,
                                                const float* __restrict__ b_rel,
                                                const int* __restrict__ batch,
                                                int* __restrict__ g_i) {
    const int tid  = threadIdx.x;
    const int lane = tid & 63;
    const int wave = tid >> 6;
    const int quad = lane >> 4;
    const int l15  = lane & 15;
    const int row_base = blockIdx.x * 128 + wave * 32;

    // Load all A fragments once: af[mf][kc], chunk index within row = kc'*4 + quad
    short8 af[2][6];
#pragma unroll
    for (int mf = 0; mf < 2; mf++) {
        int r = row_base + mf * 16 + l15;
        if (r < N_NODES) {
            const short8* ar = reinterpret_cast<const short8*>(aggb + r * 96);
            const short8* xr = reinterpret_cast<const short8*>(xb + r * 96);
            af[mf][0] = ar[0 * 4 + quad];
            af[mf][1] = ar[1 * 4 + quad];
            af[mf][2] = ar[2 * 4 + quad];
            af[mf][3] = xr[0 * 4 + quad];
            af[mf][4] = xr[1 * 4 + quad];
            af[mf][5] = xr[2 * 4 + quad];
        } else {
#pragma unroll
            for (int kc = 0; kc < 6; kc++) af[mf][kc] = (short8)0;
        }
    }

    bool fast = (row_base + 31 < N_NODES) && (batch[row_base] == batch[row_base + 31]);

#pragma unroll
    for (int ng = 0; ng < 4; ng++) {
        const int n0 = ng * 64;
        floatx4 acc[2][4];
#pragma unroll
        for (int i = 0; i < 2; i++)
#pragma unroll
            for (int j = 0; j < 4; j++) acc[i][j] = (floatx4)0.0f;

#pragma unroll
        for (int kc = 0; kc < 6; kc++) {
            short8 bf4[4];
#pragma unroll
            for (int nf = 0; nf < 4; nf++)
                bf4[nf] = *reinterpret_cast<const short8*>(
                    wt + (n0 + nf * 16 + l15) * 192 + kc * 32 + quad * 8);
#pragma unroll
            for (int mf = 0; mf < 2; mf++)
#pragma unroll
                for (int nf = 0; nf < 4; nf++)
                    acc[mf][nf] = __builtin_amdgcn_mfma_f32_16x16x32_bf16(
                        af[mf][kc], bf4[nf], acc[mf][nf], 0, 0, 0);
        }

        // Epilogue for this 64-col slice
        if (fast) {
            int gid = batch[row_base];
#pragma unroll
            for (int nf = 0; nf < 4; nf++) {
                float m = acc[0][nf][0];
#pragma unroll
                for (int mf = 0; mf < 2; mf++)
#pragma unroll
                    for (int r = 0; r < 4; r++) m = fmaxf(m, acc[mf][nf][r]);
                m = fmaxf(m, __shfl_xor(m, 16));
                m = fmaxf(m, __shfl_xor(m, 32));
                if (quad == 0) {
                    int n = n0 + nf * 16 + l15;
                    float v = fmaxf(m + b_rel[n], 0.0f);
                    atomicMax(&g_i[gid * 256 + n], __float_as_int(v));
                }
            }
        } else {
#pragma unroll
            for (int mf = 0; mf < 2; mf++) {
                int rb = row_base + mf * 16 + quad * 4;
                if (rb >= N_NODES) continue;
                bool merged = (rb + 3 < N_NODES) && (batch[rb] == batch[rb + 3]);
                if (merged) {
                    int gid = batch[rb];
#pragma unroll
                    for (int nf = 0; nf < 4; nf++) {
                        float m = fmaxf(fmaxf(acc[mf][nf][0], acc[mf][nf][1]),
                                        fmaxf(acc[mf][nf][2], acc[mf][nf][3]));
                        int n = n0 + nf * 16 + l15;
                        float v = fmaxf(m + b_rel[n], 0.0f);
                        atomicMax(&g_i[gid * 256 + n], __float_as_int(v));
                    }
                } else {
                    for (int r = 0; r < 4; r++) {
                        int rg = rb + r;
                        if (rg >= N_NODES) break;
                        int gid = batch[rg];
#pragma unroll
                        for (int nf = 0; nf < 4; nf++) {
                            int n = n0 + nf * 16 + l15;
                            float v = fmaxf(acc[mf][nf][r] + b_rel[n], 0.0f);
                            atomicMax(&g_i[gid * 256 + n], __float_as_int(v));
                        }
                    }
                }
            }
        }
    }
}

// ---------------- K4: g2 = relu(g @ W1 + b1). grid 512: (graph, n-half). 1 out/thread.
__global__ __launch_bounds__(256) void k_mlp1(const float* __restrict__ g,
                                              const float* __restrict__ W1,
                                              const float* __restrict__ b1,
                                              float* __restrict__ g2) {
    __shared__ float sg[256];
    int m  = blockIdx.x >> 1;
    int nh = (blockIdx.x & 1) * 256;
    int t  = threadIdx.x;
    sg[t] = g[m * 256 + t];
    __syncthreads();
    int n = nh + t;
    float acc = 0.f;
#pragma unroll 4
    for (int k4 = 0; k4 < 64; k4++) {
        float4 a = reinterpret_cast<const float4*>(sg)[k4];
        int k = k4 * 4;
        float w0 = W1[(k + 0) * 512 + n];
        float w1 = W1[(k + 1) * 512 + n];
        float w2 = W1[(k + 2) * 512 + n];
        float w3 = W1[(k + 3) * 512 + n];
        acc += a.x * w0 + a.y * w1 + a.z * w2 + a.w * w3;
    }
    g2[m * 512 + n] = fmaxf(acc + b1[n], 0.f);
}

// ---------------- K5: out = g2 @ W2 + b2. grid (128,3): 2 graphs x 256 outs/block.
__global__ __launch_bounds__(256) void k_mlp2(const float* __restrict__ g2,
                                              const float* __restrict__ W2,
                                              const float* __restrict__ b2,
                                              float* __restrict__ out) {
    __shared__ float sg[2 * 512];
    int m0 = blockIdx.x * 2;
    int n  = blockIdx.y * 256 + threadIdx.x;
    int t  = threadIdx.x;
#pragma unroll
    for (int i = 0; i < 4; i++) sg[t + i * 256] = g2[m0 * 512 + t + i * 256];
    __syncthreads();
    float a0 = 0.f, a1 = 0.f;
#pragma unroll 4
    for (int k4 = 0; k4 < 128; k4++) {
        float4 u = reinterpret_cast<const float4*>(sg)[k4];
        float4 v = reinterpret_cast<const float4*>(sg + 512)[k4];
        int k = k4 * 4;
        float w0 = W2[(k + 0) * 768 + n];
        float w1 = W2[(k + 1) * 768 + n];
        float w2 = W2[(k + 2) * 768 + n];
        float w3 = W2[(k + 3) * 768 + n];
        a0 += u.x * w0 + u.y * w1 + u.z * w2 + u.w * w3;
        a1 += v.x * w0 + v.y * w1 + v.z * w2 + v.w * w3;
    }
    float b = b2[n];
    out[(m0 + 0) * 768 + n] = a0 + b;
    out[(m0 + 1) * 768 + n] = a1 + b;
}

extern "C" void kernel_launch(void* const* d_in, const int* in_sizes, int n_in,
                              void* d_out, int out_size, void* d_ws, size_t ws_size,
                              hipStream_t stream) {
    const float* x      = (const float*)d_in[0];
    const int*   ei     = (const int*)d_in[1];
    const int*   batch  = (const int*)d_in[2];
    const float* W_rel  = (const float*)d_in[3];
    const float* b_rel  = (const float*)d_in[4];
    const float* W_root = (const float*)d_in[5];
    const float* W1     = (const float*)d_in[6];
    const float* b1     = (const float*)d_in[7];
    const float* W2     = (const float*)d_in[8];
    const float* b2     = (const float*)d_in[9];
    float* out = (float*)d_out;

    char* ws = (char*)d_ws;
    unsigned short* xb   = (unsigned short*)(ws);            //  9,600,000 B
    unsigned short* aggb = (unsigned short*)(ws + 9600000);  //  9,600,000 B
    float* g   = (float*)(ws + 19200000);                    //    262,144 B
    int*   deg = (int*)  (ws + 19462144);                    //    200,000 B
    int*   off = (int*)  (ws + 19662144);                    //    200,016 B
    int*   cur = (int*)  (ws + 19862160);                    //    200,000 B
    int*   es  = (int*)  (ws + 20062160);                    //  3,200,000 B
    float* g2  = (float*)(ws + 23262160);                    //    524,288 B
    unsigned short* wt = (unsigned short*)(ws + 23786448);   //     98,304 B

    // zero g (atomicMax) + deg (histogram) — contiguous
    hipMemsetAsync(ws + 19200000, 0, 262144 + 200000, stream);

    k_prep<<<2344, 256, 0, stream>>>(x, xb);
    k_transpose_w<<<192, 256, 0, stream>>>(W_rel, W_root, wt);
    k_hist<<<(N_EDGES + 255) / 256, 256, 0, stream>>>(ei, deg);
    k_scan<<<1, 1024, 0, stream>>>(deg, off, cur);
    k_fill<<<(N_EDGES + 255) / 256, 256, 0, stream>>>(ei, cur, es);
    k_gather<<<(N_NODES * 12 + 255) / 256, 256, 0, stream>>>(off, es, xb, aggb);
    k_gnn<<<391, 256, 0, stream>>>(aggb, xb, wt, b_rel, batch, (int*)g);
    k_mlp1<<<512, 256, 0, stream>>>(g, W1, b1, g2);
    k_mlp2<<<dim3(128, 3), 256, 0, stream>>>(g2, W2, b2, out);
}

// Round 5
// 220.120 us; speedup vs baseline: 5.4426x; 1.4099x over previous
//
#include <hip/hip_runtime.h>

constexpr int N_NODES = 50000;
constexpr int N_EDGES = 800000;
constexpr int NBINS   = 782;     // ceil(50000/64), 64 nodes per bin
constexpr int PBINS   = 1024;    // padded for int4 scan

typedef __attribute__((ext_vector_type(8))) short short8;
typedef __attribute__((ext_vector_type(8))) unsigned short ushort8;
typedef __attribute__((ext_vector_type(4))) float floatx4;

static __device__ __forceinline__ unsigned short f2bf(float f) {
    unsigned u = __float_as_uint(f);
    u += 0x7FFF + ((u >> 16) & 1);
    return (unsigned short)(u >> 16);
}
static __device__ __forceinline__ float bf2f(unsigned short s) {
    return __uint_as_float(((unsigned)s) << 16);
}

// ---------------- K_p: x fp32 -> bf16
__global__ __launch_bounds__(256) void k_prep(const float* __restrict__ x,
                                              unsigned short* __restrict__ xb) {
    int idx = blockIdx.x * 256 + threadIdx.x;          // 600000 chunks of 8
    if (idx >= N_NODES * 96 / 8) return;
    const float4* p = reinterpret_cast<const float4*>(x) + idx * 2;
    float4 u = p[0], v = p[1];
    short8 a;
    a[0] = (short)f2bf(u.x); a[1] = (short)f2bf(u.y);
    a[2] = (short)f2bf(u.z); a[3] = (short)f2bf(u.w);
    a[4] = (short)f2bf(v.x); a[5] = (short)f2bf(v.y);
    a[6] = (short)f2bf(v.z); a[7] = (short)f2bf(v.w);
    reinterpret_cast<short8*>(xb)[idx] = a;
}

// ---------------- K_t: Wt[n][k] = bf16(Wcat[k][n])
__global__ __launch_bounds__(256) void k_transpose_w(const float* __restrict__ Wrel,
                                                     const float* __restrict__ Wroot,
                                                     unsigned short* __restrict__ wt) {
    int idx = blockIdx.x * 256 + threadIdx.x;          // 49152
    int k = idx % 192;
    int n = idx / 192;
    float v = (k < 96) ? Wrel[k * 256 + n] : Wroot[(k - 96) * 256 + n];
    wt[idx] = f2bf(v);
}

// ---------------- bin histogram (LDS-staged), 2048 edges/block
__global__ __launch_bounds__(256) void k_hist_bin(const int* __restrict__ ei,
                                                  int* __restrict__ bin_tot) {
    __shared__ int h[NBINS];
    int t = threadIdx.x;
    for (int b = t; b < NBINS; b += 256) h[b] = 0;
    __syncthreads();
    int e0 = blockIdx.x * 2048;
#pragma unroll
    for (int i = 0; i < 8; i++) {
        int e = e0 + i * 256 + t;
        if (e < N_EDGES) atomicAdd(&h[ei[N_EDGES + e] >> 6], 1);
    }
    __syncthreads();
    for (int b = t; b < NBINS; b += 256)
        if (h[b]) atomicAdd(&bin_tot[b], h[b]);
}

// ---------------- scan of padded 1024 bins (single block, 256 thr x int4)
__global__ __launch_bounds__(256) void k_scan_bin(const int* __restrict__ bin_tot,
                                                  int* __restrict__ bin_off,
                                                  int* __restrict__ bin_cur) {
    __shared__ int wsum[4];
    int t = threadIdx.x, lane = t & 63, w = t >> 6;
    int4 d = reinterpret_cast<const int4*>(bin_tot)[t];
    int v = d.x + d.y + d.z + d.w;
    int s = v;
#pragma unroll
    for (int dd = 1; dd < 64; dd <<= 1) {
        int o = __shfl_up(s, dd);
        if (lane >= dd) s += o;
    }
    if (lane == 63) wsum[w] = s;
    __syncthreads();
    if (t == 0) {
        int r = 0;
#pragma unroll
        for (int k = 0; k < 4; k++) { int c = wsum[k]; wsum[k] = r; r += c; }
    }
    __syncthreads();
    int e0 = wsum[w] + (s - v);
    int4 o;
    o.x = e0; o.y = o.x + d.x; o.z = o.y + d.y; o.w = o.z + d.z;
    reinterpret_cast<int4*>(bin_off)[t] = o;
    reinterpret_cast<int4*>(bin_cur)[t] = o;
}

// ---------------- binned fill: per-block reservation -> temporally clustered,
// per-line-single-writer scatter of packed (src<<6)|local words.
__global__ __launch_bounds__(256) void k_fill_bin(const int* __restrict__ ei,
                                                  int* __restrict__ bin_cur,
                                                  int* __restrict__ eb) {
    __shared__ int h[NBINS];
    __shared__ int gbase[NBINS];
    int t = threadIdx.x;
    for (int b = t; b < NBINS; b += 256) h[b] = 0;
    __syncthreads();
    int e0 = blockIdx.x * 6144;
#pragma unroll
    for (int i = 0; i < 24; i++) {
        int e = e0 + i * 256 + t;
        if (e < N_EDGES) atomicAdd(&h[ei[N_EDGES + e] >> 6], 1);
    }
    __syncthreads();
    for (int b = t; b < NBINS; b += 256) {
        int c = h[b];
        gbase[b] = c ? atomicAdd(&bin_cur[b], c) : 0;
        h[b] = 0;
    }
    __syncthreads();
#pragma unroll
    for (int i = 0; i < 24; i++) {
        int e = e0 + i * 256 + t;
        if (e < N_EDGES) {
            int s = ei[e];
            int d = ei[N_EDGES + e];
            int bin = d >> 6;
            int p = gbase[bin] + atomicAdd(&h[bin], 1);
            eb[p] = (s << 6) | (d & 63);
        }
    }
}

// ---------------- per-bin gather: LDS counting-sort by local node, then
// register-accumulated gather. One block per bin; thread = (node, colgroup).
__global__ __launch_bounds__(256) void k_gatherbin(const int* __restrict__ bin_off,
                                                   const int* __restrict__ eb,
                                                   const unsigned short* __restrict__ xb,
                                                   unsigned short* __restrict__ aggb) {
    __shared__ int h[64], base[64], cursor[64];
    __shared__ int list[2048];
    int b = blockIdx.x, t = threadIdx.x;
    int s0 = bin_off[b], s1 = bin_off[b + 1];
    int node = t >> 2, cg = t & 3;
    const ushort8* xv = reinterpret_cast<const ushort8*>(xb);
    float acc[24];
#pragma unroll
    for (int j = 0; j < 24; j++) acc[j] = 0.f;

    for (int cs = s0; cs < s1; cs += 2048) {
        int cnt = min(2048, s1 - cs);
        if (t < 64) h[t] = 0;
        __syncthreads();
        for (int i = t; i < cnt; i += 256) atomicAdd(&h[eb[cs + i] & 63], 1);
        __syncthreads();
        if (t < 64) {
            int v = h[t], s = v;
#pragma unroll
            for (int dd = 1; dd < 64; dd <<= 1) {
                int o = __shfl_up(s, dd);
                if (t >= dd) s += o;
            }
            base[t] = s - v;
            cursor[t] = s - v;
        }
        __syncthreads();
        for (int i = t; i < cnt; i += 256) {
            int m = eb[cs + i];
            int p = atomicAdd(&cursor[m & 63], 1);
            list[p] = m >> 6;
        }
        __syncthreads();
        int deg = h[node], lb = base[node];
        for (int e = 0; e < deg; e++) {
            int src = list[lb + e];
            const ushort8* xr = xv + src * 12 + cg * 3;
            ushort8 a = xr[0], c1 = xr[1], c2 = xr[2];
#pragma unroll
            for (int j = 0; j < 8; j++) {
                acc[j]      += bf2f(a[j]);
                acc[8 + j]  += bf2f(c1[j]);
                acc[16 + j] += bf2f(c2[j]);
            }
        }
        __syncthreads();
    }

    int ng = b * 64 + node;
    if (ng < N_NODES) {
        short8 r0, r1, r2;
#pragma unroll
        for (int j = 0; j < 8; j++) {
            r0[j] = (short)f2bf(acc[j]);
            r1[j] = (short)f2bf(acc[8 + j]);
            r2[j] = (short)f2bf(acc[16 + j]);
        }
        short8* outp = reinterpret_cast<short8*>(aggb) + ng * 12 + cg * 3;
        outp[0] = r0; outp[1] = r1; outp[2] = r2;
    }
}

// ---------------- K3: h = relu([agg|x] @ Wcat + b_rel), fused segment-max into g
__global__ __launch_bounds__(256, 3) void k_gnn(const unsigned short* __restrict__ aggb,
                                                const unsigned short* __restrict__ xb,
                                                const unsigned short* __restrict__ wt,
                                                const float* __restrict__ b_rel,
                                                const int* __restrict__ batch,
                                                int* __restrict__ g_i) {
    const int tid  = threadIdx.x;
    const int lane = tid & 63;
    const int wave = tid >> 6;
    const int quad = lane >> 4;
    const int l15  = lane & 15;
    const int row_base = blockIdx.x * 128 + wave * 32;

    short8 af[2][6];
#pragma unroll
    for (int mf = 0; mf < 2; mf++) {
        int r = row_base + mf * 16 + l15;
        if (r < N_NODES) {
            const short8* ar = reinterpret_cast<const short8*>(aggb + r * 96);
            const short8* xr = reinterpret_cast<const short8*>(xb + r * 96);
            af[mf][0] = ar[0 * 4 + quad];
            af[mf][1] = ar[1 * 4 + quad];
            af[mf][2] = ar[2 * 4 + quad];
            af[mf][3] = xr[0 * 4 + quad];
            af[mf][4] = xr[1 * 4 + quad];
            af[mf][5] = xr[2 * 4 + quad];
        } else {
#pragma unroll
            for (int kc = 0; kc < 6; kc++) af[mf][kc] = (short8)0;
        }
    }

    bool fast = (row_base + 31 < N_NODES) && (batch[row_base] == batch[row_base + 31]);

#pragma unroll
    for (int ng = 0; ng < 4; ng++) {
        const int n0 = ng * 64;
        floatx4 acc[2][4];
#pragma unroll
        for (int i = 0; i < 2; i++)
#pragma unroll
            for (int j = 0; j < 4; j++) acc[i][j] = (floatx4)0.0f;

#pragma unroll
        for (int kc = 0; kc < 6; kc++) {
            short8 bf4[4];
#pragma unroll
            for (int nf = 0; nf < 4; nf++)
                bf4[nf] = *reinterpret_cast<const short8*>(
                    wt + (n0 + nf * 16 + l15) * 192 + kc * 32 + quad * 8);
#pragma unroll
            for (int mf = 0; mf < 2; mf++)
#pragma unroll
                for (int nf = 0; nf < 4; nf++)
                    acc[mf][nf] = __builtin_amdgcn_mfma_f32_16x16x32_bf16(
                        af[mf][kc], bf4[nf], acc[mf][nf], 0, 0, 0);
        }

        if (fast) {
            int gid = batch[row_base];
#pragma unroll
            for (int nf = 0; nf < 4; nf++) {
                float m = acc[0][nf][0];
#pragma unroll
                for (int mf = 0; mf < 2; mf++)
#pragma unroll
                    for (int r = 0; r < 4; r++) m = fmaxf(m, acc[mf][nf][r]);
                m = fmaxf(m, __shfl_xor(m, 16));
                m = fmaxf(m, __shfl_xor(m, 32));
                if (quad == 0) {
                    int n = n0 + nf * 16 + l15;
                    float v = fmaxf(m + b_rel[n], 0.0f);
                    atomicMax(&g_i[gid * 256 + n], __float_as_int(v));
                }
            }
        } else {
#pragma unroll
            for (int mf = 0; mf < 2; mf++) {
                int rb = row_base + mf * 16 + quad * 4;
                if (rb >= N_NODES) continue;
                bool merged = (rb + 3 < N_NODES) && (batch[rb] == batch[rb + 3]);
                if (merged) {
                    int gid = batch[rb];
#pragma unroll
                    for (int nf = 0; nf < 4; nf++) {
                        float m = fmaxf(fmaxf(acc[mf][nf][0], acc[mf][nf][1]),
                                        fmaxf(acc[mf][nf][2], acc[mf][nf][3]));
                        int n = n0 + nf * 16 + l15;
                        float v = fmaxf(m + b_rel[n], 0.0f);
                        atomicMax(&g_i[gid * 256 + n], __float_as_int(v));
                    }
                } else {
                    for (int r = 0; r < 4; r++) {
                        int rg = rb + r;
                        if (rg >= N_NODES) break;
                        int gid = batch[rg];
#pragma unroll
                        for (int nf = 0; nf < 4; nf++) {
                            int n = n0 + nf * 16 + l15;
                            float v = fmaxf(acc[mf][nf][r] + b_rel[n], 0.0f);
                            atomicMax(&g_i[gid * 256 + n], __float_as_int(v));
                        }
                    }
                }
            }
        }
    }
}

// ---------------- K4: g2 = relu(g @ W1 + b1)
__global__ __launch_bounds__(256) void k_mlp1(const float* __restrict__ g,
                                              const float* __restrict__ W1,
                                              const float* __restrict__ b1,
                                              float* __restrict__ g2) {
    __shared__ float sg[256];
    int m  = blockIdx.x >> 1;
    int nh = (blockIdx.x & 1) * 256;
    int t  = threadIdx.x;
    sg[t] = g[m * 256 + t];
    __syncthreads();
    int n = nh + t;
    float acc = 0.f;
#pragma unroll 4
    for (int k4 = 0; k4 < 64; k4++) {
        float4 a = reinterpret_cast<const float4*>(sg)[k4];
        int k = k4 * 4;
        float w0 = W1[(k + 0) * 512 + n];
        float w1 = W1[(k + 1) * 512 + n];
        float w2 = W1[(k + 2) * 512 + n];
        float w3 = W1[(k + 3) * 512 + n];
        acc += a.x * w0 + a.y * w1 + a.z * w2 + a.w * w3;
    }
    g2[m * 512 + n] = fmaxf(acc + b1[n], 0.f);
}

// ---------------- K5: out = g2 @ W2 + b2
__global__ __launch_bounds__(256) void k_mlp2(const float* __restrict__ g2,
                                              const float* __restrict__ W2,
                                              const float* __restrict__ b2,
                                              float* __restrict__ out) {
    __shared__ float sg[2 * 512];
    int m0 = blockIdx.x * 2;
    int n  = blockIdx.y * 256 + threadIdx.x;
    int t  = threadIdx.x;
#pragma unroll
    for (int i = 0; i < 4; i++) sg[t + i * 256] = g2[m0 * 512 + t + i * 256];
    __syncthreads();
    float a0 = 0.f, a1 = 0.f;
#pragma unroll 4
    for (int k4 = 0; k4 < 128; k4++) {
        float4 u = reinterpret_cast<const float4*>(sg)[k4];
        float4 v = reinterpret_cast<const float4*>(sg + 512)[k4];
        int k = k4 * 4;
        float w0 = W2[(k + 0) * 768 + n];
        float w1 = W2[(k + 1) * 768 + n];
        float w2 = W2[(k + 2) * 768 + n];
        float w3 = W2[(k + 3) * 768 + n];
        a0 += u.x * w0 + u.y * w1 + u.z * w2 + u.w * w3;
        a1 += v.x * w0 + v.y * w1 + v.z * w2 + v.w * w3;
    }
    float b = b2[n];
    out[(m0 + 0) * 768 + n] = a0 + b;
    out[(m0 + 1) * 768 + n] = a1 + b;
}

extern "C" void kernel_launch(void* const* d_in, const int* in_sizes, int n_in,
                              void* d_out, int out_size, void* d_ws, size_t ws_size,
                              hipStream_t stream) {
    const float* x      = (const float*)d_in[0];
    const int*   ei     = (const int*)d_in[1];
    const int*   batch  = (const int*)d_in[2];
    const float* W_rel  = (const float*)d_in[3];
    const float* b_rel  = (const float*)d_in[4];
    const float* W_root = (const float*)d_in[5];
    const float* W1     = (const float*)d_in[6];
    const float* b1     = (const float*)d_in[7];
    const float* W2     = (const float*)d_in[8];
    const float* b2     = (const float*)d_in[9];
    float* out = (float*)d_out;

    char* ws = (char*)d_ws;
    unsigned short* xb   = (unsigned short*)(ws);            //  9,600,000
    unsigned short* aggb = (unsigned short*)(ws + 9600000);  //  9,600,000
    float* g       = (float*)(ws + 19200000);                //    262,144
    int* bin_tot   = (int*)  (ws + 19462144);                //      4,096 (padded 1024)
    int* bin_off   = (int*)  (ws + 19466240);                //      4,096
    int* bin_cur   = (int*)  (ws + 19470336);                //      4,096
    int* eb        = (int*)  (ws + 19474432);                //  3,200,000
    float* g2      = (float*)(ws + 22674432);                //    524,288
    unsigned short* wt = (unsigned short*)(ws + 23198720);   //     98,304

    // zero g (atomicMax) + bin_tot (padded) — contiguous
    hipMemsetAsync(ws + 19200000, 0, 262144 + 4096, stream);

    k_prep<<<2344, 256, 0, stream>>>(x, xb);
    k_transpose_w<<<192, 256, 0, stream>>>(W_rel, W_root, wt);
    k_hist_bin<<<391, 256, 0, stream>>>(ei, bin_tot);
    k_scan_bin<<<1, 256, 0, stream>>>(bin_tot, bin_off, bin_cur);
    k_fill_bin<<<131, 256, 0, stream>>>(ei, bin_cur, eb);
    k_gatherbin<<<NBINS, 256, 0, stream>>>(bin_off, eb, xb, aggb);
    k_gnn<<<391, 256, 0, stream>>>(aggb, xb, wt, b_rel, batch, (int*)g);
    k_mlp1<<<512, 256, 0, stream>>>(g, W1, b1, g2);
    k_mlp2<<<dim3(128, 3), 256, 0, stream>>>(g2, W2, b2, out);
}

// Round 6
// 208.612 us; speedup vs baseline: 5.7428x; 1.0552x over previous
//
#include <hip/hip_runtime.h>

constexpr int N_NODES = 50000;
constexpr int N_EDGES = 800000;
constexpr int NBINS   = 782;     // ceil(50000/64), 64 nodes per bin

typedef __attribute__((ext_vector_type(8))) short short8;
typedef __attribute__((ext_vector_type(8))) unsigned short ushort8;
typedef __attribute__((ext_vector_type(4))) float floatx4;

static __device__ __forceinline__ unsigned short f2bf(float f) {
    unsigned u = __float_as_uint(f);
    u += 0x7FFF + ((u >> 16) & 1);
    return (unsigned short)(u >> 16);
}
static __device__ __forceinline__ float bf2f(unsigned short s) {
    return __uint_as_float(((unsigned)s) << 16);
}

// ---------------- K_p: x fp32 -> bf16; also zeroes g (atomicMax init) and bin_tot
__global__ __launch_bounds__(256) void k_prep(const float* __restrict__ x,
                                              unsigned short* __restrict__ xb,
                                              float* __restrict__ g,
                                              int* __restrict__ bin_tot) {
    int idx = blockIdx.x * 256 + threadIdx.x;          // 600000 chunks of 8
    if (idx < 16384) {
        reinterpret_cast<float4*>(g)[idx] = make_float4(0.f, 0.f, 0.f, 0.f);
    } else if (idx < 16640) {
        reinterpret_cast<int4*>(bin_tot)[idx - 16384] = make_int4(0, 0, 0, 0);
    }
    if (idx >= N_NODES * 96 / 8) return;
    const float4* p = reinterpret_cast<const float4*>(x) + idx * 2;
    float4 u = p[0], v = p[1];
    short8 a;
    a[0] = (short)f2bf(u.x); a[1] = (short)f2bf(u.y);
    a[2] = (short)f2bf(u.z); a[3] = (short)f2bf(u.w);
    a[4] = (short)f2bf(v.x); a[5] = (short)f2bf(v.y);
    a[6] = (short)f2bf(v.z); a[7] = (short)f2bf(v.w);
    reinterpret_cast<short8*>(xb)[idx] = a;
}

// ---------------- K_t: Wt[n][k] = bf16(Wcat[k][n])
__global__ __launch_bounds__(256) void k_transpose_w(const float* __restrict__ Wrel,
                                                     const float* __restrict__ Wroot,
                                                     unsigned short* __restrict__ wt) {
    int idx = blockIdx.x * 256 + threadIdx.x;          // 49152
    int k = idx % 192;
    int n = idx / 192;
    float v = (k < 96) ? Wrel[k * 256 + n] : Wroot[(k - 96) * 256 + n];
    wt[idx] = f2bf(v);
}

// ---------------- bin histogram (LDS-staged), 2048 edges/block
__global__ __launch_bounds__(256) void k_hist_bin(const int* __restrict__ ei,
                                                  int* __restrict__ bin_tot) {
    __shared__ int h[NBINS];
    int t = threadIdx.x;
    for (int b = t; b < NBINS; b += 256) h[b] = 0;
    __syncthreads();
    int e0 = blockIdx.x * 2048;
#pragma unroll
    for (int i = 0; i < 8; i++) {
        int e = e0 + i * 256 + t;
        if (e < N_EDGES) atomicAdd(&h[ei[N_EDGES + e] >> 6], 1);
    }
    __syncthreads();
    for (int b = t; b < NBINS; b += 256)
        if (h[b]) atomicAdd(&bin_tot[b], h[b]);
}

// ---------------- scan of padded 1024 bins (single block, 256 thr x int4)
__global__ __launch_bounds__(256) void k_scan_bin(const int* __restrict__ bin_tot,
                                                  int* __restrict__ bin_off,
                                                  int* __restrict__ bin_cur) {
    __shared__ int wsum[4];
    int t = threadIdx.x, lane = t & 63, w = t >> 6;
    int4 d = reinterpret_cast<const int4*>(bin_tot)[t];
    int v = d.x + d.y + d.z + d.w;
    int s = v;
#pragma unroll
    for (int dd = 1; dd < 64; dd <<= 1) {
        int o = __shfl_up(s, dd);
        if (lane >= dd) s += o;
    }
    if (lane == 63) wsum[w] = s;
    __syncthreads();
    if (t == 0) {
        int r = 0;
#pragma unroll
        for (int k = 0; k < 4; k++) { int c = wsum[k]; wsum[k] = r; r += c; }
    }
    __syncthreads();
    int e0 = wsum[w] + (s - v);
    int4 o;
    o.x = e0; o.y = o.x + d.x; o.z = o.y + d.y; o.w = o.z + d.z;
    reinterpret_cast<int4*>(bin_off)[t] = o;
    reinterpret_cast<int4*>(bin_cur)[t] = o;
}

// ---------------- binned fill: per-block reservation -> temporally clustered,
// per-line-single-writer scatter of packed (src<<6)|local words.
__global__ __launch_bounds__(256) void k_fill_bin(const int* __restrict__ ei,
                                                  int* __restrict__ bin_cur,
                                                  int* __restrict__ eb) {
    __shared__ int h[NBINS];
    __shared__ int gbase[NBINS];
    int t = threadIdx.x;
    for (int b = t; b < NBINS; b += 256) h[b] = 0;
    __syncthreads();
    int e0 = blockIdx.x * 6144;
#pragma unroll
    for (int i = 0; i < 24; i++) {
        int e = e0 + i * 256 + t;
        if (e < N_EDGES) atomicAdd(&h[ei[N_EDGES + e] >> 6], 1);
    }
    __syncthreads();
    for (int b = t; b < NBINS; b += 256) {
        int c = h[b];
        gbase[b] = c ? atomicAdd(&bin_cur[b], c) : 0;
        h[b] = 0;
    }
    __syncthreads();
#pragma unroll
    for (int i = 0; i < 24; i++) {
        int e = e0 + i * 256 + t;
        if (e < N_EDGES) {
            int s = ei[e];
            int d = ei[N_EDGES + e];
            int bin = d >> 6;
            int p = gbase[bin] + atomicAdd(&h[bin], 1);
            eb[p] = (s << 6) | (d & 63);
        }
    }
}

// ---------------- per-bin gather: LDS counting-sort by local node, then
// register-accumulated gather. One block per bin; thread = (node, colgroup).
__global__ __launch_bounds__(256) void k_gatherbin(const int* __restrict__ bin_off,
                                                   const int* __restrict__ eb,
                                                   const unsigned short* __restrict__ xb,
                                                   unsigned short* __restrict__ aggb) {
    __shared__ int h[64], base[64], cursor[64];
    __shared__ int list[2048];
    int b = blockIdx.x, t = threadIdx.x;
    int s0 = bin_off[b], s1 = bin_off[b + 1];
    int node = t >> 2, cg = t & 3;
    const ushort8* xv = reinterpret_cast<const ushort8*>(xb);
    float acc[24];
#pragma unroll
    for (int j = 0; j < 24; j++) acc[j] = 0.f;

    for (int cs = s0; cs < s1; cs += 2048) {
        int cnt = min(2048, s1 - cs);
        if (t < 64) h[t] = 0;
        __syncthreads();
        for (int i = t; i < cnt; i += 256) atomicAdd(&h[eb[cs + i] & 63], 1);
        __syncthreads();
        if (t < 64) {
            int v = h[t], s = v;
#pragma unroll
            for (int dd = 1; dd < 64; dd <<= 1) {
                int o = __shfl_up(s, dd);
                if (t >= dd) s += o;
            }
            base[t] = s - v;
            cursor[t] = s - v;
        }
        __syncthreads();
        for (int i = t; i < cnt; i += 256) {
            int m = eb[cs + i];
            int p = atomicAdd(&cursor[m & 63], 1);
            list[p] = m >> 6;
        }
        __syncthreads();
        int deg = h[node], lb = base[node];
        for (int e = 0; e < deg; e++) {
            int src = list[lb + e];
            const ushort8* xr = xv + src * 12 + cg * 3;
            ushort8 a = xr[0], c1 = xr[1], c2 = xr[2];
#pragma unroll
            for (int j = 0; j < 8; j++) {
                acc[j]      += bf2f(a[j]);
                acc[8 + j]  += bf2f(c1[j]);
                acc[16 + j] += bf2f(c2[j]);
            }
        }
        __syncthreads();
    }

    int ng = b * 64 + node;
    if (ng < N_NODES) {
        short8 r0, r1, r2;
#pragma unroll
        for (int j = 0; j < 8; j++) {
            r0[j] = (short)f2bf(acc[j]);
            r1[j] = (short)f2bf(acc[8 + j]);
            r2[j] = (short)f2bf(acc[16 + j]);
        }
        short8* outp = reinterpret_cast<short8*>(aggb) + ng * 12 + cg * 3;
        outp[0] = r0; outp[1] = r1; outp[2] = r2;
    }
}

// ---------------- K3: h = relu([agg|x] @ Wcat + b_rel), fused segment-max into g
// grid (391, 4): block = 128 rows x 64 cols, wave = 32 rows x 64 cols.
// A-frags resident in regs (48 VGPR); __launch_bounds__(256,4) caps VGPR at 128
// -> 4 waves/SIMD, grid provides 6.1 blocks/CU (24 waves/CU possible).
__global__ __launch_bounds__(256, 4) void k_gnn(const unsigned short* __restrict__ aggb,
                                                const unsigned short* __restrict__ xb,
                                                const unsigned short* __restrict__ wt,
                                                const float* __restrict__ b_rel,
                                                const int* __restrict__ batch,
                                                int* __restrict__ g_i) {
    const int tid  = threadIdx.x;
    const int lane = tid & 63;
    const int wave = tid >> 6;
    const int quad = lane >> 4;
    const int l15  = lane & 15;
    const int row_base = blockIdx.x * 128 + wave * 32;
    const int n0 = blockIdx.y * 64;

    short8 af[2][6];
#pragma unroll
    for (int mf = 0; mf < 2; mf++) {
        int r = row_base + mf * 16 + l15;
        if (r < N_NODES) {
            const short8* ar = reinterpret_cast<const short8*>(aggb + r * 96);
            const short8* xr = reinterpret_cast<const short8*>(xb + r * 96);
            af[mf][0] = ar[0 * 4 + quad];
            af[mf][1] = ar[1 * 4 + quad];
            af[mf][2] = ar[2 * 4 + quad];
            af[mf][3] = xr[0 * 4 + quad];
            af[mf][4] = xr[1 * 4 + quad];
            af[mf][5] = xr[2 * 4 + quad];
        } else {
#pragma unroll
            for (int kc = 0; kc < 6; kc++) af[mf][kc] = (short8)0;
        }
    }

    floatx4 acc[2][4];
#pragma unroll
    for (int i = 0; i < 2; i++)
#pragma unroll
        for (int j = 0; j < 4; j++) acc[i][j] = (floatx4)0.0f;

#pragma unroll
    for (int kc = 0; kc < 6; kc++) {
        short8 bf4[4];
#pragma unroll
        for (int nf = 0; nf < 4; nf++)
            bf4[nf] = *reinterpret_cast<const short8*>(
                wt + (n0 + nf * 16 + l15) * 192 + kc * 32 + quad * 8);
#pragma unroll
        for (int mf = 0; mf < 2; mf++)
#pragma unroll
            for (int nf = 0; nf < 4; nf++)
                acc[mf][nf] = __builtin_amdgcn_mfma_f32_16x16x32_bf16(
                    af[mf][kc], bf4[nf], acc[mf][nf], 0, 0, 0);
    }

    bool fast = (row_base + 31 < N_NODES) && (batch[row_base] == batch[row_base + 31]);
    if (fast) {
        int gid = batch[row_base];
#pragma unroll
        for (int nf = 0; nf < 4; nf++) {
            float m = acc[0][nf][0];
#pragma unroll
            for (int mf = 0; mf < 2; mf++)
#pragma unroll
                for (int r = 0; r < 4; r++) m = fmaxf(m, acc[mf][nf][r]);
            m = fmaxf(m, __shfl_xor(m, 16));
            m = fmaxf(m, __shfl_xor(m, 32));
            if (quad == 0) {
                int n = n0 + nf * 16 + l15;
                float v = fmaxf(m + b_rel[n], 0.0f);
                atomicMax(&g_i[gid * 256 + n], __float_as_int(v));
            }
        }
    } else {
#pragma unroll
        for (int mf = 0; mf < 2; mf++) {
            int rb = row_base + mf * 16 + quad * 4;
            if (rb >= N_NODES) continue;
            bool merged = (rb + 3 < N_NODES) && (batch[rb] == batch[rb + 3]);
            if (merged) {
                int gid = batch[rb];
#pragma unroll
                for (int nf = 0; nf < 4; nf++) {
                    float m = fmaxf(fmaxf(acc[mf][nf][0], acc[mf][nf][1]),
                                    fmaxf(acc[mf][nf][2], acc[mf][nf][3]));
                    int n = n0 + nf * 16 + l15;
                    float v = fmaxf(m + b_rel[n], 0.0f);
                    atomicMax(&g_i[gid * 256 + n], __float_as_int(v));
                }
            } else {
                for (int r = 0; r < 4; r++) {
                    int rg = rb + r;
                    if (rg >= N_NODES) break;
                    int gid = batch[rg];
#pragma unroll
                    for (int nf = 0; nf < 4; nf++) {
                        int n = n0 + nf * 16 + l15;
                        float v = fmaxf(acc[mf][nf][r] + b_rel[n], 0.0f);
                        atomicMax(&g_i[gid * 256 + n], __float_as_int(v));
                    }
                }
            }
        }
    }
}

// ---------------- K4: g2 = relu(g @ W1 + b1)
__global__ __launch_bounds__(256) void k_mlp1(const float* __restrict__ g,
                                              const float* __restrict__ W1,
                                              const float* __restrict__ b1,
                                              float* __restrict__ g2) {
    __shared__ float sg[256];
    int m  = blockIdx.x >> 1;
    int nh = (blockIdx.x & 1) * 256;
    int t  = threadIdx.x;
    sg[t] = g[m * 256 + t];
    __syncthreads();
    int n = nh + t;
    float acc = 0.f;
#pragma unroll 4
    for (int k4 = 0; k4 < 64; k4++) {
        float4 a = reinterpret_cast<const float4*>(sg)[k4];
        int k = k4 * 4;
        float w0 = W1[(k + 0) * 512 + n];
        float w1 = W1[(k + 1) * 512 + n];
        float w2 = W1[(k + 2) * 512 + n];
        float w3 = W1[(k + 3) * 512 + n];
        acc += a.x * w0 + a.y * w1 + a.z * w2 + a.w * w3;
    }
    g2[m * 512 + n] = fmaxf(acc + b1[n], 0.f);
}

// ---------------- K5: out = g2 @ W2 + b2
__global__ __launch_bounds__(256) void k_mlp2(const float* __restrict__ g2,
                                              const float* __restrict__ W2,
                                              const float* __restrict__ b2,
                                              float* __restrict__ out) {
    __shared__ float sg[2 * 512];
    int m0 = blockIdx.x * 2;
    int n  = blockIdx.y * 256 + threadIdx.x;
    int t  = threadIdx.x;
#pragma unroll
    for (int i = 0; i < 4; i++) sg[t + i * 256] = g2[m0 * 512 + t + i * 256];
    __syncthreads();
    float a0 = 0.f, a1 = 0.f;
#pragma unroll 4
    for (int k4 = 0; k4 < 128; k4++) {
        float4 u = reinterpret_cast<const float4*>(sg)[k4];
        float4 v = reinterpret_cast<const float4*>(sg + 512)[k4];
        int k = k4 * 4;
        float w0 = W2[(k + 0) * 768 + n];
        float w1 = W2[(k + 1) * 768 + n];
        float w2 = W2[(k + 2) * 768 + n];
        float w3 = W2[(k + 3) * 768 + n];
        a0 += u.x * w0 + u.y * w1 + u.z * w2 + u.w * w3;
        a1 += v.x * w0 + v.y * w1 + v.z * w2 + v.w * w3;
    }
    float b = b2[n];
    out[(m0 + 0) * 768 + n] = a0 + b;
    out[(m0 + 1) * 768 + n] = a1 + b;
}

extern "C" void kernel_launch(void* const* d_in, const int* in_sizes, int n_in,
                              void* d_out, int out_size, void* d_ws, size_t ws_size,
                              hipStream_t stream) {
    const float* x      = (const float*)d_in[0];
    const int*   ei     = (const int*)d_in[1];
    const int*   batch  = (const int*)d_in[2];
    const float* W_rel  = (const float*)d_in[3];
    const float* b_rel  = (const float*)d_in[4];
    const float* W_root = (const float*)d_in[5];
    const float* W1     = (const float*)d_in[6];
    const float* b1     = (const float*)d_in[7];
    const float* W2     = (const float*)d_in[8];
    const float* b2     = (const float*)d_in[9];
    float* out = (float*)d_out;

    char* ws = (char*)d_ws;
    unsigned short* xb   = (unsigned short*)(ws);            //  9,600,000
    unsigned short* aggb = (unsigned short*)(ws + 9600000);  //  9,600,000
    float* g       = (float*)(ws + 19200000);                //    262,144
    int* bin_tot   = (int*)  (ws + 19462144);                //      4,096 (padded 1024)
    int* bin_off   = (int*)  (ws + 19466240);                //      4,096
    int* bin_cur   = (int*)  (ws + 19470336);                //      4,096
    int* eb        = (int*)  (ws + 19474432);                //  3,200,000
    float* g2      = (float*)(ws + 22674432);                //    524,288
    unsigned short* wt = (unsigned short*)(ws + 23198720);   //     98,304

    k_prep<<<2344, 256, 0, stream>>>(x, xb, g, bin_tot);
    k_transpose_w<<<192, 256, 0, stream>>>(W_rel, W_root, wt);
    k_hist_bin<<<391, 256, 0, stream>>>(ei, bin_tot);
    k_scan_bin<<<1, 256, 0, stream>>>(bin_tot, bin_off, bin_cur);
    k_fill_bin<<<131, 256, 0, stream>>>(ei, bin_cur, eb);
    k_gatherbin<<<NBINS, 256, 0, stream>>>(bin_off, eb, xb, aggb);
    k_gnn<<<dim3(391, 4), 256, 0, stream>>>(aggb, xb, wt, b_rel, batch, (int*)g);
    k_mlp1<<<512, 256, 0, stream>>>(g, W1, b1, g2);
    k_mlp2<<<dim3(128, 3), 256, 0, stream>>>(g2, W2, b2, out);
}

// Round 7
// 197.550 us; speedup vs baseline: 6.0644x; 1.0560x over previous
//
#include <hip/hip_runtime.h>

constexpr int N_NODES = 50000;
constexpr int N_EDGES = 800000;
constexpr int NBINS   = 782;     // ceil(50000/64), 64 nodes per bin
constexpr int BINCAP  = 1536;    // mean 1024, sd 32 -> +16 sigma, never overflows

typedef __attribute__((ext_vector_type(8))) short short8;
typedef __attribute__((ext_vector_type(8))) unsigned short ushort8;
typedef __attribute__((ext_vector_type(4))) float floatx4;

static __device__ __forceinline__ unsigned short f2bf(float f) {
    unsigned u = __float_as_uint(f);
    u += 0x7FFF + ((u >> 16) & 1);
    return (unsigned short)(u >> 16);
}
static __device__ __forceinline__ float bf2f(unsigned short s) {
    return __uint_as_float(((unsigned)s) << 16);
}

// ---------------- K_p: x fp32 -> bf16; W transpose->bf16; zero g and bin_cnt
__global__ __launch_bounds__(256) void k_prep(const float* __restrict__ x,
                                              unsigned short* __restrict__ xb,
                                              const float* __restrict__ Wrel,
                                              const float* __restrict__ Wroot,
                                              unsigned short* __restrict__ wt,
                                              float* __restrict__ g,
                                              int* __restrict__ bin_cnt) {
    int idx = blockIdx.x * 256 + threadIdx.x;          // 600064 threads
    if (idx < 49152) {                                  // Wt[n][k] = bf16(Wcat[k][n])
        int k = idx % 192;
        int n = idx / 192;
        float v = (k < 96) ? Wrel[k * 256 + n] : Wroot[(k - 96) * 256 + n];
        wt[idx] = f2bf(v);
    }
    if (idx < 16384) {
        reinterpret_cast<float4*>(g)[idx] = make_float4(0.f, 0.f, 0.f, 0.f);
    } else if (idx < 16384 + 196) {                     // 784 ints >= NBINS
        reinterpret_cast<int4*>(bin_cnt)[idx - 16384] = make_int4(0, 0, 0, 0);
    }
    if (idx >= N_NODES * 96 / 8) return;
    const float4* p = reinterpret_cast<const float4*>(x) + idx * 2;
    float4 u = p[0], v = p[1];
    short8 a;
    a[0] = (short)f2bf(u.x); a[1] = (short)f2bf(u.y);
    a[2] = (short)f2bf(u.z); a[3] = (short)f2bf(u.w);
    a[4] = (short)f2bf(v.x); a[5] = (short)f2bf(v.y);
    a[6] = (short)f2bf(v.z); a[7] = (short)f2bf(v.w);
    reinterpret_cast<short8*>(xb)[idx] = a;
}

// ---------------- binned fill, fixed-capacity bins (no global scan needed):
// per-block LDS histogram -> one reservation atomic per touched bin ->
// temporally-clustered packed writes of (src<<6)|local into bin region.
__global__ __launch_bounds__(256) void k_fill_bin(const int* __restrict__ ei,
                                                  int* __restrict__ bin_cnt,
                                                  int* __restrict__ eb) {
    __shared__ int h[NBINS];
    __shared__ int gbase[NBINS];
    int t = threadIdx.x;
    for (int b = t; b < NBINS; b += 256) h[b] = 0;
    __syncthreads();
    int e0 = blockIdx.x * 6144;
#pragma unroll
    for (int i = 0; i < 24; i++) {
        int e = e0 + i * 256 + t;
        if (e < N_EDGES) atomicAdd(&h[ei[N_EDGES + e] >> 6], 1);
    }
    __syncthreads();
    for (int b = t; b < NBINS; b += 256) {
        int c = h[b];
        gbase[b] = c ? atomicAdd(&bin_cnt[b], c) : 0;
        h[b] = 0;
    }
    __syncthreads();
#pragma unroll
    for (int i = 0; i < 24; i++) {
        int e = e0 + i * 256 + t;
        if (e < N_EDGES) {
            int s = ei[e];
            int d = ei[N_EDGES + e];
            int bin = d >> 6;
            int p = gbase[bin] + atomicAdd(&h[bin], 1);
            eb[bin * BINCAP + p] = (s << 6) | (d & 63);
        }
    }
}

// ---------------- per-bin gather: LDS counting-sort by local node, then
// register-accumulated gather (x2 unrolled). One block per bin.
__global__ __launch_bounds__(256) void k_gatherbin(const int* __restrict__ bin_cnt,
                                                   const int* __restrict__ eb,
                                                   const unsigned short* __restrict__ xb,
                                                   unsigned short* __restrict__ aggb) {
    __shared__ int h[64], base[64], cursor[64];
    __shared__ int list[2048];
    int b = blockIdx.x, t = threadIdx.x;
    int total = bin_cnt[b];
    const int* ebb = eb + b * BINCAP;
    int node = t >> 2, cg = t & 3;
    const ushort8* xv = reinterpret_cast<const ushort8*>(xb);
    float acc[24];
#pragma unroll
    for (int j = 0; j < 24; j++) acc[j] = 0.f;

    for (int cs = 0; cs < total; cs += 2048) {
        int cnt = min(2048, total - cs);
        if (t < 64) h[t] = 0;
        __syncthreads();
        for (int i = t; i < cnt; i += 256) atomicAdd(&h[ebb[cs + i] & 63], 1);
        __syncthreads();
        if (t < 64) {
            int v = h[t], s = v;
#pragma unroll
            for (int dd = 1; dd < 64; dd <<= 1) {
                int o = __shfl_up(s, dd);
                if (t >= dd) s += o;
            }
            base[t] = s - v;
            cursor[t] = s - v;
        }
        __syncthreads();
        for (int i = t; i < cnt; i += 256) {
            int m = ebb[cs + i];
            int p = atomicAdd(&cursor[m & 63], 1);
            list[p] = m >> 6;
        }
        __syncthreads();
        int deg = h[node], lb = base[node];
        int e = 0;
        for (; e + 2 <= deg; e += 2) {
            int s0 = list[lb + e], s1 = list[lb + e + 1];
            const ushort8* x0 = xv + s0 * 12 + cg * 3;
            const ushort8* x1 = xv + s1 * 12 + cg * 3;
            ushort8 a0 = x0[0], b0 = x0[1], c0 = x0[2];
            ushort8 a1 = x1[0], b1 = x1[1], c1 = x1[2];
#pragma unroll
            for (int j = 0; j < 8; j++) {
                acc[j]      += bf2f(a0[j]) + bf2f(a1[j]);
                acc[8 + j]  += bf2f(b0[j]) + bf2f(b1[j]);
                acc[16 + j] += bf2f(c0[j]) + bf2f(c1[j]);
            }
        }
        if (e < deg) {
            int s0 = list[lb + e];
            const ushort8* x0 = xv + s0 * 12 + cg * 3;
            ushort8 a0 = x0[0], b0 = x0[1], c0 = x0[2];
#pragma unroll
            for (int j = 0; j < 8; j++) {
                acc[j]      += bf2f(a0[j]);
                acc[8 + j]  += bf2f(b0[j]);
                acc[16 + j] += bf2f(c0[j]);
            }
        }
        __syncthreads();
    }

    int ng = b * 64 + node;
    if (ng < N_NODES) {
        short8 r0, r1, r2;
#pragma unroll
        for (int j = 0; j < 8; j++) {
            r0[j] = (short)f2bf(acc[j]);
            r1[j] = (short)f2bf(acc[8 + j]);
            r2[j] = (short)f2bf(acc[16 + j]);
        }
        short8* outp = reinterpret_cast<short8*>(aggb) + ng * 12 + cg * 3;
        outp[0] = r0; outp[1] = r1; outp[2] = r2;
    }
}

// ---------------- K3: h = relu([agg|x] @ Wcat + b_rel), fused segment-max into g
// grid (391, 4): block = 128 rows x 64 cols, wave = 32 rows x 64 cols.
__global__ __launch_bounds__(256, 4) void k_gnn(const unsigned short* __restrict__ aggb,
                                                const unsigned short* __restrict__ xb,
                                                const unsigned short* __restrict__ wt,
                                                const float* __restrict__ b_rel,
                                                const int* __restrict__ batch,
                                                int* __restrict__ g_i) {
    const int tid  = threadIdx.x;
    const int lane = tid & 63;
    const int wave = tid >> 6;
    const int quad = lane >> 4;
    const int l15  = lane & 15;
    const int row_base = blockIdx.x * 128 + wave * 32;
    const int n0 = blockIdx.y * 64;

    short8 af[2][6];
#pragma unroll
    for (int mf = 0; mf < 2; mf++) {
        int r = row_base + mf * 16 + l15;
        if (r < N_NODES) {
            const short8* ar = reinterpret_cast<const short8*>(aggb + r * 96);
            const short8* xr = reinterpret_cast<const short8*>(xb + r * 96);
            af[mf][0] = ar[0 * 4 + quad];
            af[mf][1] = ar[1 * 4 + quad];
            af[mf][2] = ar[2 * 4 + quad];
            af[mf][3] = xr[0 * 4 + quad];
            af[mf][4] = xr[1 * 4 + quad];
            af[mf][5] = xr[2 * 4 + quad];
        } else {
#pragma unroll
            for (int kc = 0; kc < 6; kc++) af[mf][kc] = (short8)0;
        }
    }

    floatx4 acc[2][4];
#pragma unroll
    for (int i = 0; i < 2; i++)
#pragma unroll
        for (int j = 0; j < 4; j++) acc[i][j] = (floatx4)0.0f;

#pragma unroll
    for (int kc = 0; kc < 6; kc++) {
        short8 bf4[4];
#pragma unroll
        for (int nf = 0; nf < 4; nf++)
            bf4[nf] = *reinterpret_cast<const short8*>(
                wt + (n0 + nf * 16 + l15) * 192 + kc * 32 + quad * 8);
#pragma unroll
        for (int mf = 0; mf < 2; mf++)
#pragma unroll
            for (int nf = 0; nf < 4; nf++)
                acc[mf][nf] = __builtin_amdgcn_mfma_f32_16x16x32_bf16(
                    af[mf][kc], bf4[nf], acc[mf][nf], 0, 0, 0);
    }

    bool fast = (row_base + 31 < N_NODES) && (batch[row_base] == batch[row_base + 31]);
    if (fast) {
        int gid = batch[row_base];
#pragma unroll
        for (int nf = 0; nf < 4; nf++) {
            float m = acc[0][nf][0];
#pragma unroll
            for (int mf = 0; mf < 2; mf++)
#pragma unroll
                for (int r = 0; r < 4; r++) m = fmaxf(m, acc[mf][nf][r]);
            m = fmaxf(m, __shfl_xor(m, 16));
            m = fmaxf(m, __shfl_xor(m, 32));
            if (quad == 0) {
                int n = n0 + nf * 16 + l15;
                float v = fmaxf(m + b_rel[n], 0.0f);
                atomicMax(&g_i[gid * 256 + n], __float_as_int(v));
            }
        }
    } else {
#pragma unroll
        for (int mf = 0; mf < 2; mf++) {
            int rb = row_base + mf * 16 + quad * 4;
            if (rb >= N_NODES) continue;
            bool merged = (rb + 3 < N_NODES) && (batch[rb] == batch[rb + 3]);
            if (merged) {
                int gid = batch[rb];
#pragma unroll
                for (int nf = 0; nf < 4; nf++) {
                    float m = fmaxf(fmaxf(acc[mf][nf][0], acc[mf][nf][1]),
                                    fmaxf(acc[mf][nf][2], acc[mf][nf][3]));
                    int n = n0 + nf * 16 + l15;
                    float v = fmaxf(m + b_rel[n], 0.0f);
                    atomicMax(&g_i[gid * 256 + n], __float_as_int(v));
                }
            } else {
                for (int r = 0; r < 4; r++) {
                    int rg = rb + r;
                    if (rg >= N_NODES) break;
                    int gid = batch[rg];
#pragma unroll
                    for (int nf = 0; nf < 4; nf++) {
                        int n = n0 + nf * 16 + l15;
                        float v = fmaxf(acc[mf][nf][r] + b_rel[n], 0.0f);
                        atomicMax(&g_i[gid * 256 + n], __float_as_int(v));
                    }
                }
            }
        }
    }
}

// ---------------- K4: g2 = relu(g @ W1 + b1)
__global__ __launch_bounds__(256) void k_mlp1(const float* __restrict__ g,
                                              const float* __restrict__ W1,
                                              const float* __restrict__ b1,
                                              float* __restrict__ g2) {
    __shared__ float sg[256];
    int m  = blockIdx.x >> 1;
    int nh = (blockIdx.x & 1) * 256;
    int t  = threadIdx.x;
    sg[t] = g[m * 256 + t];
    __syncthreads();
    int n = nh + t;
    float acc = 0.f;
#pragma unroll 4
    for (int k4 = 0; k4 < 64; k4++) {
        float4 a = reinterpret_cast<const float4*>(sg)[k4];
        int k = k4 * 4;
        float w0 = W1[(k + 0) * 512 + n];
        float w1 = W1[(k + 1) * 512 + n];
        float w2 = W1[(k + 2) * 512 + n];
        float w3 = W1[(k + 3) * 512 + n];
        acc += a.x * w0 + a.y * w1 + a.z * w2 + a.w * w3;
    }
    g2[m * 512 + n] = fmaxf(acc + b1[n], 0.f);
}

// ---------------- K5: out = g2 @ W2 + b2
__global__ __launch_bounds__(256) void k_mlp2(const float* __restrict__ g2,
                                              const float* __restrict__ W2,
                                              const float* __restrict__ b2,
                                              float* __restrict__ out) {
    __shared__ float sg[2 * 512];
    int m0 = blockIdx.x * 2;
    int n  = blockIdx.y * 256 + threadIdx.x;
    int t  = threadIdx.x;
#pragma unroll
    for (int i = 0; i < 4; i++) sg[t + i * 256] = g2[m0 * 512 + t + i * 256];
    __syncthreads();
    float a0 = 0.f, a1 = 0.f;
#pragma unroll 4
    for (int k4 = 0; k4 < 128; k4++) {
        float4 u = reinterpret_cast<const float4*>(sg)[k4];
        float4 v = reinterpret_cast<const float4*>(sg + 512)[k4];
        int k = k4 * 4;
        float w0 = W2[(k + 0) * 768 + n];
        float w1 = W2[(k + 1) * 768 + n];
        float w2 = W2[(k + 2) * 768 + n];
        float w3 = W2[(k + 3) * 768 + n];
        a0 += u.x * w0 + u.y * w1 + u.z * w2 + u.w * w3;
        a1 += v.x * w0 + v.y * w1 + v.z * w2 + v.w * w3;
    }
    float b = b2[n];
    out[(m0 + 0) * 768 + n] = a0 + b;
    out[(m0 + 1) * 768 + n] = a1 + b;
}

extern "C" void kernel_launch(void* const* d_in, const int* in_sizes, int n_in,
                              void* d_out, int out_size, void* d_ws, size_t ws_size,
                              hipStream_t stream) {
    const float* x      = (const float*)d_in[0];
    const int*   ei     = (const int*)d_in[1];
    const int*   batch  = (const int*)d_in[2];
    const float* W_rel  = (const float*)d_in[3];
    const float* b_rel  = (const float*)d_in[4];
    const float* W_root = (const float*)d_in[5];
    const float* W1     = (const float*)d_in[6];
    const float* b1     = (const float*)d_in[7];
    const float* W2     = (const float*)d_in[8];
    const float* b2     = (const float*)d_in[9];
    float* out = (float*)d_out;

    char* ws = (char*)d_ws;
    unsigned short* xb   = (unsigned short*)(ws);            //  9,600,000
    unsigned short* aggb = (unsigned short*)(ws + 9600000);  //  9,600,000
    float* g       = (float*)(ws + 19200000);                //    262,144
    int* bin_cnt   = (int*)  (ws + 19462144);                //      3,136 (784 ints)
    int* eb        = (int*)  (ws + 19465280);                //  4,804,608 (782*1536*4)
    float* g2      = (float*)(ws + 24269888);                //    524,288
    unsigned short* wt = (unsigned short*)(ws + 24794176);   //     98,304

    k_prep<<<2344, 256, 0, stream>>>(x, xb, W_rel, W_root, wt, g, bin_cnt);
    k_fill_bin<<<131, 256, 0, stream>>>(ei, bin_cnt, eb);
    k_gatherbin<<<NBINS, 256, 0, stream>>>(bin_cnt, eb, xb, aggb);
    k_gnn<<<dim3(391, 4), 256, 0, stream>>>(aggb, xb, wt, b_rel, batch, (int*)g);
    k_mlp1<<<512, 256, 0, stream>>>(g, W1, b1, g2);
    k_mlp2<<<dim3(128, 3), 256, 0, stream>>>(g2, W2, b2, out);
}

// Round 10
// 194.144 us; speedup vs baseline: 6.1708x; 1.0175x over previous
//
#include <hip/hip_runtime.h>

constexpr int N_NODES = 50000;
constexpr int N_EDGES = 800000;
constexpr int NBINS   = 782;     // ceil(50000/64), 64 nodes per bin
constexpr int BINCAP  = 1536;    // mean 1024, sd 32 -> +16 sigma, never overflows

typedef __attribute__((ext_vector_type(8))) short short8;
typedef __attribute__((ext_vector_type(8))) unsigned short ushort8;
typedef __attribute__((ext_vector_type(4))) float floatx4;

static __device__ __forceinline__ unsigned short f2bf(float f) {
    unsigned u = __float_as_uint(f);
    u += 0x7FFF + ((u >> 16) & 1);
    return (unsigned short)(u >> 16);
}
static __device__ __forceinline__ float bf2f(unsigned short s) {
    return __uint_as_float(((unsigned)s) << 16);
}

// ---------------- K_p: x fp32 -> bf16; W transpose->bf16; zero g and bin_cnt
__global__ __launch_bounds__(256) void k_prep(const float* __restrict__ x,
                                              unsigned short* __restrict__ xb,
                                              const float* __restrict__ Wrel,
                                              const float* __restrict__ Wroot,
                                              unsigned short* __restrict__ wt,
                                              float* __restrict__ g,
                                              int* __restrict__ bin_cnt) {
    int idx = blockIdx.x * 256 + threadIdx.x;
    if (idx < 49152) {                                  // Wt[n][k] = bf16(Wcat[k][n])
        int k = idx % 192;
        int n = idx / 192;
        float v = (k < 96) ? Wrel[k * 256 + n] : Wroot[(k - 96) * 256 + n];
        wt[idx] = f2bf(v);
    }
    if (idx < 16384) {
        reinterpret_cast<float4*>(g)[idx] = make_float4(0.f, 0.f, 0.f, 0.f);
    } else if (idx < 16384 + 196) {                     // 784 ints >= NBINS
        reinterpret_cast<int4*>(bin_cnt)[idx - 16384] = make_int4(0, 0, 0, 0);
    }
    if (idx >= N_NODES * 96 / 8) return;
    const float4* p = reinterpret_cast<const float4*>(x) + idx * 2;
    float4 u = p[0], v = p[1];
    short8 a;
    a[0] = (short)f2bf(u.x); a[1] = (short)f2bf(u.y);
    a[2] = (short)f2bf(u.z); a[3] = (short)f2bf(u.w);
    a[4] = (short)f2bf(v.x); a[5] = (short)f2bf(v.y);
    a[6] = (short)f2bf(v.z); a[7] = (short)f2bf(v.w);
    reinterpret_cast<short8*>(xb)[idx] = a;
}

// ---------------- binned fill, fixed-capacity bins (OOB-hardened)
__global__ __launch_bounds__(256) void k_fill_bin(const int* __restrict__ ei,
                                                  int* __restrict__ bin_cnt,
                                                  int* __restrict__ eb) {
    __shared__ int h[NBINS];
    __shared__ int gbase[NBINS];
    int t = threadIdx.x;
    for (int b = t; b < NBINS; b += 256) h[b] = 0;
    __syncthreads();
    int e0 = blockIdx.x * 6144;
#pragma unroll
    for (int i = 0; i < 24; i++) {
        int e = e0 + i * 256 + t;
        if (e < N_EDGES) atomicAdd(&h[ei[N_EDGES + e] >> 6], 1);
    }
    __syncthreads();
    for (int b = t; b < NBINS; b += 256) {
        int c = h[b];
        gbase[b] = c ? atomicAdd(&bin_cnt[b], c) : 0;
        h[b] = 0;
    }
    __syncthreads();
#pragma unroll
    for (int i = 0; i < 24; i++) {
        int e = e0 + i * 256 + t;
        if (e < N_EDGES) {
            int s = ei[e];
            int d = ei[N_EDGES + e];
            int bin = d >> 6;
            int p = gbase[bin] + atomicAdd(&h[bin], 1);
            if (p < BINCAP)                       // hardening: never write OOB
                eb[bin * BINCAP + p] = (s << 6) | (d & 63);
        }
    }
}

// ---------------- fused gather + GEMM + pool. One block per bin (64 rows).
// Phase 1: LDS counting-sort of bin's edges. Phase 2: register gather of
// sum(x[src]) -> bf16 A-tile in LDS (row stride 104 -> 2-way b128 conflicts,
// free). Phase 3: 4 waves x 64-col MFMA slices (M=64). Phase 4: segment-max.
__global__ __launch_bounds__(256, 4) void k_gnn(const int* __restrict__ bin_cnt,
                                                const int* __restrict__ eb,
                                                const unsigned short* __restrict__ xb,
                                                const unsigned short* __restrict__ wt,
                                                const float* __restrict__ b_rel,
                                                const int* __restrict__ batch,
                                                int* __restrict__ g_i) {
    __shared__ int h[64], base[64], cursor[64];
    __shared__ int list[BINCAP];
    __shared__ unsigned short at[64 * 104];   // agg tile, padded row stride
    const int b = blockIdx.x, t = threadIdx.x;
    const int total = min(bin_cnt[b], BINCAP); // hardening: never read/sort OOB
    const int* ebb = eb + b * BINCAP;

    // ---- phase 1: counting sort by local node
    if (t < 64) h[t] = 0;
    __syncthreads();
    for (int i = t; i < total; i += 256) atomicAdd(&h[ebb[i] & 63], 1);
    __syncthreads();
    if (t < 64) {
        int v = h[t], s = v;
#pragma unroll
        for (int dd = 1; dd < 64; dd <<= 1) {
            int o = __shfl_up(s, dd);
            if (t >= dd) s += o;
        }
        base[t] = s - v;
        cursor[t] = s - v;
    }
    __syncthreads();
    for (int i = t; i < total; i += 256) {
        int m = ebb[i];
        int p = atomicAdd(&cursor[m & 63], 1);
        list[p] = m >> 6;
    }
    __syncthreads();

    // ---- phase 2: gather (thread = node x colgroup of 24), x2 unrolled
    {
        int node = t >> 2, cg = t & 3;
        const ushort8* xv = reinterpret_cast<const ushort8*>(xb);
        float acc[24];
#pragma unroll
        for (int j = 0; j < 24; j++) acc[j] = 0.f;
        int deg = h[node], lb = base[node];
        int e = 0;
        for (; e + 2 <= deg; e += 2) {
            int s0 = list[lb + e], s1 = list[lb + e + 1];
            const ushort8* x0 = xv + s0 * 12 + cg * 3;
            const ushort8* x1 = xv + s1 * 12 + cg * 3;
            ushort8 a0 = x0[0], b0 = x0[1], c0 = x0[2];
            ushort8 a1 = x1[0], b1 = x1[1], c1 = x1[2];
#pragma unroll
            for (int j = 0; j < 8; j++) {
                acc[j]      += bf2f(a0[j]) + bf2f(a1[j]);
                acc[8 + j]  += bf2f(b0[j]) + bf2f(b1[j]);
                acc[16 + j] += bf2f(c0[j]) + bf2f(c1[j]);
            }
        }
        if (e < deg) {
            int s0 = list[lb + e];
            const ushort8* x0 = xv + s0 * 12 + cg * 3;
            ushort8 a0 = x0[0], b0 = x0[1], c0 = x0[2];
#pragma unroll
            for (int j = 0; j < 8; j++) {
                acc[j]      += bf2f(a0[j]);
                acc[8 + j]  += bf2f(b0[j]);
                acc[16 + j] += bf2f(c0[j]);
            }
        }
        short8 r0, r1, r2;
#pragma unroll
        for (int j = 0; j < 8; j++) {
            r0[j] = (short)f2bf(acc[j]);
            r1[j] = (short)f2bf(acc[8 + j]);
            r2[j] = (short)f2bf(acc[16 + j]);
        }
        short8* ap = reinterpret_cast<short8*>(at + node * 104 + cg * 24);
        ap[0] = r0; ap[1] = r1; ap[2] = r2;
    }
    __syncthreads();

    // ---- phase 3: GEMM 64x256x192 (wave = 64-col slice)
    const int lane = t & 63;
    const int wave = t >> 6;
    const int quad = lane >> 4;
    const int l15  = lane & 15;
    const int row_base = b * 64;
    const int n0 = wave * 64;

    floatx4 C[4][4];
#pragma unroll
    for (int i = 0; i < 4; i++)
#pragma unroll
        for (int j = 0; j < 4; j++) C[i][j] = (floatx4)0.0f;

#pragma unroll
    for (int kc = 0; kc < 6; kc++) {
        short8 a4[4];
#pragma unroll
        for (int mf = 0; mf < 4; mf++) {
            if (kc < 3) {
                a4[mf] = *reinterpret_cast<const short8*>(
                    at + (mf * 16 + l15) * 104 + kc * 32 + quad * 8);
            } else {
                int r = row_base + mf * 16 + l15;
                a4[mf] = (r < N_NODES)
                    ? *reinterpret_cast<const short8*>(xb + r * 96 + (kc - 3) * 32 + quad * 8)
                    : (short8)0;
            }
        }
        short8 b4[4];
#pragma unroll
        for (int nf = 0; nf < 4; nf++)
            b4[nf] = *reinterpret_cast<const short8*>(
                wt + (n0 + nf * 16 + l15) * 192 + kc * 32 + quad * 8);
#pragma unroll
        for (int mf = 0; mf < 4; mf++)
#pragma unroll
            for (int nf = 0; nf < 4; nf++)
                C[mf][nf] = __builtin_amdgcn_mfma_f32_16x16x32_bf16(
                    a4[mf], b4[nf], C[mf][nf], 0, 0, 0);
    }

    // ---- phase 4: bias + relu + segment-max pool
    bool fast = (row_base + 63 < N_NODES) && (batch[row_base] == batch[row_base + 63]);
    if (fast) {
        int gid = batch[row_base];
#pragma unroll
        for (int nf = 0; nf < 4; nf++) {
            float m = C[0][nf][0];
#pragma unroll
            for (int mf = 0; mf < 4; mf++)
#pragma unroll
                for (int r = 0; r < 4; r++) m = fmaxf(m, C[mf][nf][r]);
            m = fmaxf(m, __shfl_xor(m, 16));
            m = fmaxf(m, __shfl_xor(m, 32));
            if (quad == 0) {
                int n = n0 + nf * 16 + l15;
                float v = fmaxf(m + b_rel[n], 0.0f);
                atomicMax(&g_i[gid * 256 + n], __float_as_int(v));
            }
        }
    } else {
#pragma unroll
        for (int mf = 0; mf < 4; mf++) {
            int rb = row_base + mf * 16 + quad * 4;
            if (rb >= N_NODES) continue;
            bool merged = (rb + 3 < N_NODES) && (batch[rb] == batch[rb + 3]);
            if (merged) {
                int gid = batch[rb];
#pragma unroll
                for (int nf = 0; nf < 4; nf++) {
                    float m = fmaxf(fmaxf(C[mf][nf][0], C[mf][nf][1]),
                                    fmaxf(C[mf][nf][2], C[mf][nf][3]));
                    int n = n0 + nf * 16 + l15;
                    float v = fmaxf(m + b_rel[n], 0.0f);
                    atomicMax(&g_i[gid * 256 + n], __float_as_int(v));
                }
            } else {
                for (int r = 0; r < 4; r++) {
                    int rg = rb + r;
                    if (rg >= N_NODES) break;
                    int gid = batch[rg];
#pragma unroll
                    for (int nf = 0; nf < 4; nf++) {
                        int n = n0 + nf * 16 + l15;
                        float v = fmaxf(C[mf][nf][r] + b_rel[n], 0.0f);
                        atomicMax(&g_i[gid * 256 + n], __float_as_int(v));
                    }
                }
            }
        }
    }
}

// ---------------- K4: g2 = relu(g @ W1 + b1). 2 graphs x 256 outs per block.
__global__ __launch_bounds__(256) void k_mlp1(const float* __restrict__ g,
                                              const float* __restrict__ W1,
                                              const float* __restrict__ b1,
                                              float* __restrict__ g2) {
    __shared__ float sg[2 * 256];
    int m0 = (blockIdx.x >> 1) * 2;
    int nh = (blockIdx.x & 1) * 256;
    int t  = threadIdx.x;
#pragma unroll
    for (int i = 0; i < 2; i++) sg[t + i * 256] = g[m0 * 256 + t + i * 256];
    __syncthreads();
    int n = nh + t;
    float a0 = 0.f, a1 = 0.f;
#pragma unroll 4
    for (int k4 = 0; k4 < 64; k4++) {
        float4 u = reinterpret_cast<const float4*>(sg)[k4];
        float4 v = reinterpret_cast<const float4*>(sg + 256)[k4];
        int k = k4 * 4;
        float w0 = W1[(k + 0) * 512 + n];
        float w1 = W1[(k + 1) * 512 + n];
        float w2 = W1[(k + 2) * 512 + n];
        float w3 = W1[(k + 3) * 512 + n];
        a0 += u.x * w0 + u.y * w1 + u.z * w2 + u.w * w3;
        a1 += v.x * w0 + v.y * w1 + v.z * w2 + v.w * w3;
    }
    float bb = b1[n];
    g2[(m0 + 0) * 512 + n] = fmaxf(a0 + bb, 0.f);
    g2[(m0 + 1) * 512 + n] = fmaxf(a1 + bb, 0.f);
}

// ---------------- K5: out = g2 @ W2 + b2
__global__ __launch_bounds__(256) void k_mlp2(const float* __restrict__ g2,
                                              const float* __restrict__ W2,
                                              const float* __restrict__ b2,
                                              float* __restrict__ out) {
    __shared__ float sg[2 * 512];
    int m0 = blockIdx.x * 2;
    int n  = blockIdx.y * 256 + threadIdx.x;
    int t  = threadIdx.x;
#pragma unroll
    for (int i = 0; i < 4; i++) sg[t + i * 256] = g2[m0 * 512 + t + i * 256];
    __syncthreads();
    float a0 = 0.f, a1 = 0.f;
#pragma unroll 4
    for (int k4 = 0; k4 < 128; k4++) {
        float4 u = reinterpret_cast<const float4*>(sg)[k4];
        float4 v = reinterpret_cast<const float4*>(sg + 512)[k4];
        int k = k4 * 4;
        float w0 = W2[(k + 0) * 768 + n];
        float w1 = W2[(k + 1) * 768 + n];
        float w2 = W2[(k + 2) * 768 + n];
        float w3 = W2[(k + 3) * 768 + n];
        a0 += u.x * w0 + u.y * w1 + u.z * w2 + u.w * w3;
        a1 += v.x * w0 + v.y * w1 + v.z * w2 + v.w * w3;
    }
    float bb = b2[n];
    out[(m0 + 0) * 768 + n] = a0 + bb;
    out[(m0 + 1) * 768 + n] = a1 + bb;
}

extern "C" void kernel_launch(void* const* d_in, const int* in_sizes, int n_in,
                              void* d_out, int out_size, void* d_ws, size_t ws_size,
                              hipStream_t stream) {
    const float* x      = (const float*)d_in[0];
    const int*   ei     = (const int*)d_in[1];
    const int*   batch  = (const int*)d_in[2];
    const float* W_rel  = (const float*)d_in[3];
    const float* b_rel  = (const float*)d_in[4];
    const float* W_root = (const float*)d_in[5];
    const float* W1     = (const float*)d_in[6];
    const float* b1     = (const float*)d_in[7];
    const float* W2     = (const float*)d_in[8];
    const float* b2     = (const float*)d_in[9];
    float* out = (float*)d_out;

    char* ws = (char*)d_ws;
    unsigned short* xb = (unsigned short*)(ws);              //  9,600,000
    float* g       = (float*)(ws + 9600000);                 //    262,144
    int* bin_cnt   = (int*)  (ws + 9862144);                 //      3,136 (784 ints)
    int* eb        = (int*)  (ws + 9865280);                 //  4,804,608 (782*1536*4)
    float* g2      = (float*)(ws + 14669888);                //    524,288
    unsigned short* wt = (unsigned short*)(ws + 15194176);   //     98,304

    k_prep<<<2344, 256, 0, stream>>>(x, xb, W_rel, W_root, wt, g, bin_cnt);
    k_fill_bin<<<131, 256, 0, stream>>>(ei, bin_cnt, eb);
    k_gnn<<<NBINS, 256, 0, stream>>>(bin_cnt, eb, xb, wt, b_rel, batch, (int*)g);
    k_mlp1<<<256, 256, 0, stream>>>(g, W1, b1, g2);
    k_mlp2<<<dim3(128, 3), 256, 0, stream>>>(g2, W2, b2, out);
}